// Round 5
// baseline (3200.485 us; speedup 1.0000x reference)
//
#include <hip/hip_runtime.h>
#include <cstdint>
#include <cstddef>

// ---------------------------------------------------------------------------
// GCN(1 layer, sym-norm w/ self loops) -> LSTM(1 layer, T=9) -> FC, eval mode
// Round 5: k_gates_cell regeometried — 512-thr blocks, 64-row strip x full
// 512 cols (A fetched ONCE per strip, was 4x), wave = 32r x 32ch x 4 gates
// (cell fusion stays in-register). Ping-pong A planes kept.
// ---------------------------------------------------------------------------

constexpr int N    = 50000;
constexpr int NP   = 50048;  // padded to 64-row strips (782*64)
constexpr int E    = 1600000;
constexpr int T    = 9;
constexpr int H    = 128;    // F_IN == H == 128
constexpr int G    = 512;    // 4*H (gates i,f,g,o)
constexpr int OUTD = 32;

constexpr int SCAN_CH = 512;
constexpr int NCH = (N + SCAN_CH - 1) / SCAN_CH;   // 98

typedef __attribute__((ext_vector_type(8))) short bf16x8;
typedef __attribute__((ext_vector_type(4))) float f32x4;
typedef unsigned short u16;

__device__ __forceinline__ u16 f2bf(float f) {        // RNE f32 -> bf16 bits
  unsigned u = __builtin_bit_cast(unsigned, f);
  u += 0x7fffu + ((u >> 16) & 1u);
  return (u16)(u >> 16);
}
__device__ __forceinline__ float bf2f(u16 h) {
  unsigned u = ((unsigned)h) << 16;
  return __builtin_bit_cast(float, u);
}

// ---------------- degree / CSR build ----------------

__global__ void k_count(const int* __restrict__ col, int* __restrict__ cnt) {
  int e = blockIdx.x * 256 + threadIdx.x;
  if (e < E) atomicAdd(&cnt[col[e]], 1);
}

__global__ void k_dinv(const int* __restrict__ cnt, float* __restrict__ dinv) {
  int v = blockIdx.x * 256 + threadIdx.x;
  if (v < N) dinv[v] = rsqrtf((float)cnt[v] + 1.0f);   // +1 self loop
}

__global__ void k_chunk_sum(const int* __restrict__ cnt, int* __restrict__ csum) {
  __shared__ int sp[SCAN_CH / 64];
  int i = blockIdx.x * SCAN_CH + threadIdx.x;
  int v = (i < N) ? cnt[i] : 0;
  for (int off = 32; off > 0; off >>= 1) v += __shfl_down(v, off, 64);
  if ((threadIdx.x & 63) == 0) sp[threadIdx.x >> 6] = v;
  __syncthreads();
  if (threadIdx.x == 0) {
    int s = 0;
    #pragma unroll
    for (int w = 0; w < SCAN_CH / 64; ++w) s += sp[w];
    csum[blockIdx.x] = s;
  }
}

__global__ void k_chunk_scan(const int* __restrict__ csum, int* __restrict__ coff) {
  if (blockIdx.x == 0 && threadIdx.x == 0) {
    int run = 0;
    for (int b = 0; b < NCH; ++b) { coff[b] = run; run += csum[b]; }
    coff[NCH] = run;
  }
}

__global__ void k_scan_final(const int* __restrict__ cnt, const int* __restrict__ coff,
                             int* __restrict__ offv) {
  __shared__ int s[SCAN_CH];
  int tid = threadIdx.x;
  int i = blockIdx.x * SCAN_CH + tid;
  int v = (i < N) ? cnt[i] : 0;
  s[tid] = v;
  __syncthreads();
  for (int st = 1; st < SCAN_CH; st <<= 1) {
    int tv = (tid >= st) ? s[tid - st] : 0;
    __syncthreads();
    s[tid] += tv;
    __syncthreads();
  }
  if (i < N) offv[i] = coff[blockIdx.x] + s[tid] - v;   // exclusive
  if (blockIdx.x == 0 && tid == 0) offv[N] = coff[NCH];
}

__global__ void k_fill(const int* __restrict__ row, const int* __restrict__ col,
                       const float* __restrict__ dinv, const int* __restrict__ offv,
                       int* __restrict__ cursor, int* __restrict__ csr_src,
                       float* __restrict__ csr_norm) {
  int e = blockIdx.x * 256 + threadIdx.x;
  if (e >= E) return;
  int r = row[e], c = col[e];
  int p = atomicAdd(&cursor[c], 1);
  int idx = offv[c] + p;
  csr_src[idx]  = r;
  csr_norm[idx] = dinv[r] * dinv[c];
}

// ---------------- weight split/transpose (once per call) ----------------
// LSTM: Bt[j][k] (j<512, k<256): k<128 -> W_ih[j][k], else W_hh[j][k-128]
__global__ void k_wsplit_lstm(const float* __restrict__ Wih, const float* __restrict__ Whh,
                              u16* __restrict__ bhi, u16* __restrict__ blo) {
  int idx = blockIdx.x * 256 + threadIdx.x;   // 512*256
  if (idx >= G * 256) return;
  int j = idx >> 8, k = idx & 255;
  float f = (k < H) ? Wih[j * H + k] : Whh[j * H + (k - H)];
  u16 h = f2bf(f);
  u16 l = f2bf(f - bf2f(h));
  bhi[idx] = h; blo[idx] = l;
}

// GCN: Bt[j][k] = W_gcn[k][j]  (128x128)
__global__ void k_wsplit_gcn(const float* __restrict__ Wg,
                             u16* __restrict__ bhi, u16* __restrict__ blo) {
  int idx = blockIdx.x * 256 + threadIdx.x;   // 128*128
  if (idx >= H * H) return;
  int j = idx >> 7, k = idx & 127;
  float f = Wg[k * H + j];
  u16 h = f2bf(f);
  u16 l = f2bf(f - bf2f(h));
  bhi[idx] = h; blo[idx] = l;
}

// ---------------- GCN GEMM (MFMA): xw = x_t @ W_gcn ----------------
// block 256 thr = 4 waves (2x2) -> 128 rows x 128 cols; K=128 (4 kblocks).
__global__ __launch_bounds__(256) void k_gcn_mfma(const float* __restrict__ X,
                                                  const u16* __restrict__ Bhi,
                                                  const u16* __restrict__ Blo,
                                                  float* __restrict__ xw) {
  int lane = threadIdx.x & 63, wid = threadIdx.x >> 6;
  int wr = wid >> 1, wc = wid & 1;
  int rb = blockIdx.x * 128 + wr * 64;
  int cb = wc * 64;
  int lr = lane & 15;
  int lk = (lane >> 4) * 8;
  f32x4 acc[4][4];
  #pragma unroll
  for (int mi = 0; mi < 4; ++mi)
    #pragma unroll
    for (int ni = 0; ni < 4; ++ni) acc[mi][ni] = (f32x4)0.0f;

  #pragma unroll
  for (int kb = 0; kb < 4; ++kb) {
    int ko = kb * 32 + lk;
    bf16x8 bh[4], bl[4];
    #pragma unroll
    for (int ni = 0; ni < 4; ++ni) {
      size_t off = (size_t)(cb + ni * 16 + lr) * H + ko;
      bh[ni] = *reinterpret_cast<const bf16x8*>(Bhi + off);
      bl[ni] = *reinterpret_cast<const bf16x8*>(Blo + off);
    }
    #pragma unroll
    for (int mi = 0; mi < 4; ++mi) {
      int r = rb + mi * 16 + lr;
      r = r < N ? r : N - 1;                     // clamp (pad rows discarded)
      const float* ap = X + (size_t)r * H + ko;
      float4 a0 = *(const float4*)ap;
      float4 a1 = *(const float4*)(ap + 4);
      float fe[8] = {a0.x, a0.y, a0.z, a0.w, a1.x, a1.y, a1.z, a1.w};
      bf16x8 ah, al;
      #pragma unroll
      for (int e = 0; e < 8; ++e) {
        u16 hh = f2bf(fe[e]);
        ah[e] = (short)hh;
        al[e] = (short)f2bf(fe[e] - bf2f(hh));
      }
      #pragma unroll
      for (int ni = 0; ni < 4; ++ni) {
        acc[mi][ni] = __builtin_amdgcn_mfma_f32_16x16x32_bf16(ah, bh[ni], acc[mi][ni], 0, 0, 0);
        acc[mi][ni] = __builtin_amdgcn_mfma_f32_16x16x32_bf16(ah, bl[ni], acc[mi][ni], 0, 0, 0);
        acc[mi][ni] = __builtin_amdgcn_mfma_f32_16x16x32_bf16(al, bh[ni], acc[mi][ni], 0, 0, 0);
      }
    }
  }
  int orow = (lane >> 4) * 4;
  #pragma unroll
  for (int mi = 0; mi < 4; ++mi)
    #pragma unroll
    for (int ni = 0; ni < 4; ++ni)
      #pragma unroll
      for (int r = 0; r < 4; ++r) {
        int n = rb + mi * 16 + orow + r;
        if (n < N) xw[(size_t)n * H + cb + ni * 16 + lr] = acc[mi][ni][r];
      }
}

// ---------------- aggregation -> emb (bf16 hi/lo planes) ----------------
// Wave per vertex; two 32-lane halves process even/odd edges (float4/lane),
// combined via shfl_xor(32). emb written into Ahi/Alo cols 0..127.
__global__ __launch_bounds__(256) void k_agg(const float* __restrict__ xw,
                                             const int* __restrict__ offv,
                                             const int* __restrict__ csr_src,
                                             const float* __restrict__ csr_norm,
                                             const float* __restrict__ dinv,
                                             const float* __restrict__ bg,
                                             u16* __restrict__ Ahi,
                                             u16* __restrict__ Alo) {
  int wid = threadIdx.x >> 6, lane = threadIdx.x & 63;
  int v = blockIdx.x * 4 + wid;          // N % 4 == 0
  int half = lane >> 5, sl = lane & 31;
  int c0 = sl * 4;
  float ax = 0.f, ay = 0.f, az = 0.f, aw = 0.f;
  if (half == 0) {                       // self term once
    float dv = dinv[v];
    float w = dv * dv;
    float4 xs = *(const float4*)&xw[(size_t)v * H + c0];
    ax = xs.x * w; ay = xs.y * w; az = xs.z * w; aw = xs.w * w;
  }
  int e0 = offv[v], e1 = offv[v + 1];
  for (int e = e0 + half; e < e1; e += 2) {
    int s = csr_src[e]; float m = csr_norm[e];
    float4 x = *(const float4*)&xw[(size_t)s * H + c0];
    ax = fmaf(x.x, m, ax); ay = fmaf(x.y, m, ay);
    az = fmaf(x.z, m, az); aw = fmaf(x.w, m, aw);
  }
  ax += __shfl_xor(ax, 32, 64);
  ay += __shfl_xor(ay, 32, 64);
  az += __shfl_xor(az, 32, 64);
  aw += __shfl_xor(aw, 32, 64);
  float4 bb = *(const float4*)&bg[c0];
  float o0 = fmaxf(ax + bb.x, 0.f), o1 = fmaxf(ay + bb.y, 0.f);
  float o2 = fmaxf(az + bb.z, 0.f), o3 = fmaxf(aw + bb.w, 0.f);
  u16 h0 = f2bf(o0), h1 = f2bf(o1), h2 = f2bf(o2), h3 = f2bf(o3);
  size_t base = (size_t)v * 256 + c0;
  if (half == 0) {
    *(ushort4*)&Ahi[base] = make_ushort4(h0, h1, h2, h3);
  } else {
    u16 l0 = f2bf(o0 - bf2f(h0)), l1 = f2bf(o1 - bf2f(h1));
    u16 l2 = f2bf(o2 - bf2f(h2)), l3 = f2bf(o3 - bf2f(h3));
    *(ushort4*)&Alo[base] = make_ushort4(l0, l1, l2, l3);
  }
}

// ---------------- fused gates GEMM + LSTM cell ----------------
// 512-thr block = 8 waves; block tile = 64 rows x ALL 512 gate cols (A strip
// fetched once). Wave (wr: row half, wq: ch quarter) = 32 rows x 32 ch x
// 4 gates: ni = g*2+hh -> col j = g*128 + wq*32 + hh*16 + lr. acc[mi][ni]
// thus holds (i,f,g,o) for the same (row, channel) -> cell in-register.
// Reads A-cur (emb_t | h_{t-1}); writes h_t into A-nxt (ping-pong, no race).
template<bool FIRST>
__global__ __launch_bounds__(512) void k_gates_cell(const u16* __restrict__ Ahi,
                                                    const u16* __restrict__ Alo,
                                                    const u16* __restrict__ Bhi,
                                                    const u16* __restrict__ Blo,
                                                    const float* __restrict__ bih,
                                                    const float* __restrict__ bhh,
                                                    float* __restrict__ cbuf,
                                                    float* __restrict__ hbuf,
                                                    u16* __restrict__ oAhi,
                                                    u16* __restrict__ oAlo) {
  int lane = threadIdx.x & 63, wid = threadIdx.x >> 6;   // wid 0..7
  int wr = wid >> 2, wq = wid & 3;
  int rb = blockIdx.x * 64 + wr * 32;
  int chb = wq * 32;
  int lr = lane & 15;
  int lk = (lane >> 4) * 8;
  f32x4 acc[2][8];
  #pragma unroll
  for (int mi = 0; mi < 2; ++mi)
    #pragma unroll
    for (int ni = 0; ni < 8; ++ni) acc[mi][ni] = (f32x4)0.0f;

  const int KB = FIRST ? 4 : 8;          // t=0: h==0, skip upper K half
  #pragma unroll 2
  for (int kb = 0; kb < KB; ++kb) {
    int ko = kb * 32 + lk;
    bf16x8 bh[8], bl[8];
    #pragma unroll
    for (int ni = 0; ni < 8; ++ni) {     // g = ni>>1, hh = ni&1
      int j = (ni >> 1) * 128 + chb + (ni & 1) * 16 + lr;
      size_t off = (size_t)j * 256 + ko;
      bh[ni] = *reinterpret_cast<const bf16x8*>(Bhi + off);
      bl[ni] = *reinterpret_cast<const bf16x8*>(Blo + off);
    }
    #pragma unroll
    for (int mi = 0; mi < 2; ++mi) {
      size_t off = (size_t)(rb + mi * 16 + lr) * 256 + ko;
      bf16x8 ah = *reinterpret_cast<const bf16x8*>(Ahi + off);
      bf16x8 al = *reinterpret_cast<const bf16x8*>(Alo + off);
      #pragma unroll
      for (int ni = 0; ni < 8; ++ni) {
        acc[mi][ni] = __builtin_amdgcn_mfma_f32_16x16x32_bf16(ah, bh[ni], acc[mi][ni], 0, 0, 0);
        acc[mi][ni] = __builtin_amdgcn_mfma_f32_16x16x32_bf16(ah, bl[ni], acc[mi][ni], 0, 0, 0);
        acc[mi][ni] = __builtin_amdgcn_mfma_f32_16x16x32_bf16(al, bh[ni], acc[mi][ni], 0, 0, 0);
      }
    }
  }
  int orow = (lane >> 4) * 4;
  #pragma unroll
  for (int hh = 0; hh < 2; ++hh) {
    int ch = chb + hh * 16 + lr;
    float bi_ = bih[ch]       + bhh[ch];
    float bf_ = bih[128 + ch] + bhh[128 + ch];
    float bg_ = bih[256 + ch] + bhh[256 + ch];
    float bo_ = bih[384 + ch] + bhh[384 + ch];
    #pragma unroll
    for (int mi = 0; mi < 2; ++mi) {
      #pragma unroll
      for (int r = 0; r < 4; ++r) {
        int n = rb + mi * 16 + orow + r;
        if (n >= N) continue;
        float gi = acc[mi][0 + hh][r] + bi_;
        float gf = acc[mi][2 + hh][r] + bf_;
        float gg = acc[mi][4 + hh][r] + bg_;
        float go = acc[mi][6 + hh][r] + bo_;
        float si = 1.f / (1.f + expf(-gi));
        float sf = 1.f / (1.f + expf(-gf));
        float so = 1.f / (1.f + expf(-go));
        float tg = tanhf(gg);
        size_t ci = (size_t)n * H + ch;
        float cn = FIRST ? si * tg : fmaf(sf, cbuf[ci], si * tg);
        cbuf[ci] = cn;
        float hn = so * tanhf(cn);
        hbuf[ci] = hn;
        u16 hv = f2bf(hn);
        size_t ab = (size_t)n * 256 + 128 + ch;
        oAhi[ab] = hv;
        oAlo[ab] = f2bf(hn - bf2f(hv));
      }
    }
  }
}

// ---------------- FC per step: out[n][t][:] = h[n] @ W_fc^T + b_fc ----------------
__global__ __launch_bounds__(256, 3) void k_fc(const float* __restrict__ h,
                                               const float* __restrict__ Wfc,
                                               const float* __restrict__ bfc,
                                               float* __restrict__ outp, int t) {
  __shared__ float hsT[128][68];
  __shared__ float wT[128][36];
  int tid = threadIdx.x;
  int n0 = blockIdx.x * 64;
  for (int i = 0; i < 32; ++i) {
    int idx = i * 256 + tid;
    int r = idx >> 7, k = idx & 127;
    hsT[k][r] = (n0 + r < N) ? h[(size_t)(n0 + r) * H + k] : 0.0f;
  }
  for (int i = 0; i < 16; ++i) {
    int idx = i * 256 + tid;          // 4096 = 32*128
    int oc = idx >> 7, k = idx & 127;
    wT[k][oc] = Wfc[idx];
  }
  __syncthreads();
  int og = tid & 15, rg = tid >> 4;   // 16 oc-groups x 16 row-groups
  int oc0 = og * 2, r0 = rg * 4;
  float acc[4][2] = {};
  #pragma unroll 2
  for (int k = 0; k < 128; ++k) {
    float4 a = *(const float4*)&hsT[k][r0];
    float2 w = *(const float2*)&wT[k][oc0];
    float ar[4] = {a.x, a.y, a.z, a.w};
    #pragma unroll
    for (int i = 0; i < 4; ++i) {
      acc[i][0] = fmaf(ar[i], w.x, acc[i][0]);
      acc[i][1] = fmaf(ar[i], w.y, acc[i][1]);
    }
  }
  float b0 = bfc[oc0], b1 = bfc[oc0 + 1];
  #pragma unroll
  for (int i = 0; i < 4; ++i) {
    int n = n0 + r0 + i;
    if (n < N) {
      size_t ob = ((size_t)n * T + t) * OUTD + oc0;
      outp[ob]     = acc[i][0] + b0;
      outp[ob + 1] = acc[i][1] + b1;
    }
  }
}

// ---------------------------------------------------------------------------

extern "C" void kernel_launch(void* const* d_in, const int* in_sizes, int n_in,
                              void* d_out, int out_size, void* d_ws, size_t ws_size,
                              hipStream_t stream) {
  const float* x_seq = (const float*)d_in[0];
  const int*   eidx  = (const int*)d_in[1];
  const int*   erow  = eidx;          // sources
  const int*   ecol  = eidx + E;      // targets
  const float* W_gcn = (const float*)d_in[2];
  const float* b_gcn = (const float*)d_in[3];
  const float* W_ih  = (const float*)d_in[4];
  const float* W_hh  = (const float*)d_in[5];
  const float* b_ih  = (const float*)d_in[6];
  const float* b_hh  = (const float*)d_in[7];
  const float* W_fc  = (const float*)d_in[8];
  const float* b_fc  = (const float*)d_in[9];
  float* outp = (float*)d_out;

  char* base = (char*)d_ws;
  size_t o = 0;
  auto alloc = [&](size_t bytes) -> void* {
    void* p = base + o;
    o += (bytes + 255) & ~(size_t)255;
    return p;
  };
  int*   cnt      = (int*)  alloc((size_t)N * 4);
  int*   cursor   = (int*)  alloc((size_t)N * 4);
  int*   offv     = (int*)  alloc((size_t)(N + 1) * 4);
  int*   csum     = (int*)  alloc((size_t)(NCH + 1) * 4);
  int*   coff     = (int*)  alloc((size_t)(NCH + 1) * 4);
  float* dinv     = (float*)alloc((size_t)N * 4);
  int*   csr_src  = (int*)  alloc((size_t)E * 4);
  float* csr_norm = (float*)alloc((size_t)E * 4);
  u16*   bt_hi    = (u16*)  alloc((size_t)G * 256 * 2);
  u16*   bt_lo    = (u16*)  alloc((size_t)G * 256 * 2);
  u16*   bg_hi    = (u16*)  alloc((size_t)H * H * 2);
  u16*   bg_lo    = (u16*)  alloc((size_t)H * H * 2);
  u16*   a_hi0    = (u16*)  alloc((size_t)NP * 256 * 2);   // [emb | h] bf16-hi, even t
  u16*   a_lo0    = (u16*)  alloc((size_t)NP * 256 * 2);
  u16*   a_hi1    = (u16*)  alloc((size_t)NP * 256 * 2);   // odd t
  u16*   a_lo1    = (u16*)  alloc((size_t)NP * 256 * 2);
  float* xw       = (float*)alloc((size_t)N * H * 4);
  float* hbuf     = (float*)alloc((size_t)N * H * 4);
  float* cbuf     = (float*)alloc((size_t)N * H * 4);
  (void)ws_size; (void)in_sizes; (void)n_in; (void)out_size;

  u16* AHI[2] = {a_hi0, a_hi1};
  u16* ALO[2] = {a_lo0, a_lo1};

  // only the small CSR counters need zeroing; h/c state handled by the
  // FIRST-step specialization; pad rows only affect discarded output rows.
  hipMemsetAsync(cnt,    0, (size_t)N * 4, stream);
  hipMemsetAsync(cursor, 0, (size_t)N * 4, stream);

  k_count<<<E / 256, 256, 0, stream>>>(ecol, cnt);
  k_dinv<<<(N + 255) / 256, 256, 0, stream>>>(cnt, dinv);
  k_chunk_sum<<<NCH, SCAN_CH, 0, stream>>>(cnt, csum);
  k_chunk_scan<<<1, 64, 0, stream>>>(csum, coff);
  k_scan_final<<<NCH, SCAN_CH, 0, stream>>>(cnt, coff, offv);
  k_fill<<<E / 256, 256, 0, stream>>>(erow, ecol, dinv, offv, cursor, csr_src, csr_norm);
  k_wsplit_lstm<<<(G * 256) / 256, 256, 0, stream>>>(W_ih, W_hh, bt_hi, bt_lo);
  k_wsplit_gcn<<<(H * H) / 256, 256, 0, stream>>>(W_gcn, bg_hi, bg_lo);

  int gblocks = NP / 128;                 // 391, for k_gcn_mfma
  int sblocks = NP / 64;                  // 782, for k_gates_cell
  int rblocks = (N + 63) / 64;            // for k_fc
  for (int t = 0; t < T; ++t) {
    int cur = t & 1, nxt = cur ^ 1;
    const float* xt = x_seq + (size_t)t * N * H;
    k_gcn_mfma<<<gblocks, 256, 0, stream>>>(xt, bg_hi, bg_lo, xw);
    k_agg<<<N / 4, 256, 0, stream>>>(xw, offv, csr_src, csr_norm, dinv, b_gcn,
                                     AHI[cur], ALO[cur]);
    if (t == 0)
      k_gates_cell<true><<<sblocks, 512, 0, stream>>>(
          AHI[cur], ALO[cur], bt_hi, bt_lo, b_ih, b_hh, cbuf, hbuf, AHI[nxt], ALO[nxt]);
    else
      k_gates_cell<false><<<sblocks, 512, 0, stream>>>(
          AHI[cur], ALO[cur], bt_hi, bt_lo, b_ih, b_hh, cbuf, hbuf, AHI[nxt], ALO[nxt]);
    k_fc<<<rblocks, 256, 0, stream>>>(hbuf, W_fc, b_fc, outp, t);
  }
}

// Round 6
// 3082.058 us; speedup vs baseline: 1.0384x; 1.0384x over previous
//
#include <hip/hip_runtime.h>
#include <cstdint>
#include <cstddef>

// ---------------------------------------------------------------------------
// GCN(1 layer, sym-norm w/ self loops) -> LSTM(1 layer, T=9) -> FC, eval mode
// Round 6: k_gates_cell rebuilt as an LDS-staged MFMA GEMM (reg-staged single
// 32KB buffer, T14 issue-early/write-late pipeline, 2 barriers per k-block),
// gate-interleaved column tiles (cell fusion in-register), bijective
// XCD-chunked block swizzle so a row-strip's 4 col-blocks share one XCD L2.
// ---------------------------------------------------------------------------

constexpr int N    = 50000;
constexpr int NP   = 50048;  // padded to 128-row strips (391*128)
constexpr int E    = 1600000;
constexpr int T    = 9;
constexpr int H    = 128;    // F_IN == H == 128
constexpr int G    = 512;    // 4*H (gates i,f,g,o)
constexpr int OUTD = 32;

constexpr int SCAN_CH = 512;
constexpr int NCH = (N + SCAN_CH - 1) / SCAN_CH;   // 98

// gates grid: 391 row-strips x 4 col-quarters
constexpr int GNWG = (NP / 128) * 4;               // 1564
constexpr int GQQ  = GNWG / 8;                     // 195
constexpr int GRR  = GNWG % 8;                     // 4

typedef __attribute__((ext_vector_type(8))) short bf16x8;
typedef __attribute__((ext_vector_type(4))) float f32x4;
typedef unsigned short u16;

__device__ __forceinline__ u16 f2bf(float f) {        // RNE f32 -> bf16 bits
  unsigned u = __builtin_bit_cast(unsigned, f);
  u += 0x7fffu + ((u >> 16) & 1u);
  return (u16)(u >> 16);
}
__device__ __forceinline__ float bf2f(u16 h) {
  unsigned u = ((unsigned)h) << 16;
  return __builtin_bit_cast(float, u);
}

// ---------------- degree / CSR build ----------------

__global__ void k_count(const int* __restrict__ col, int* __restrict__ cnt) {
  int e = blockIdx.x * 256 + threadIdx.x;
  if (e < E) atomicAdd(&cnt[col[e]], 1);
}

__global__ void k_dinv(const int* __restrict__ cnt, float* __restrict__ dinv) {
  int v = blockIdx.x * 256 + threadIdx.x;
  if (v < N) dinv[v] = rsqrtf((float)cnt[v] + 1.0f);   // +1 self loop
}

__global__ void k_chunk_sum(const int* __restrict__ cnt, int* __restrict__ csum) {
  __shared__ int sp[SCAN_CH / 64];
  int i = blockIdx.x * SCAN_CH + threadIdx.x;
  int v = (i < N) ? cnt[i] : 0;
  for (int off = 32; off > 0; off >>= 1) v += __shfl_down(v, off, 64);
  if ((threadIdx.x & 63) == 0) sp[threadIdx.x >> 6] = v;
  __syncthreads();
  if (threadIdx.x == 0) {
    int s = 0;
    #pragma unroll
    for (int w = 0; w < SCAN_CH / 64; ++w) s += sp[w];
    csum[blockIdx.x] = s;
  }
}

__global__ void k_chunk_scan(const int* __restrict__ csum, int* __restrict__ coff) {
  if (blockIdx.x == 0 && threadIdx.x == 0) {
    int run = 0;
    for (int b = 0; b < NCH; ++b) { coff[b] = run; run += csum[b]; }
    coff[NCH] = run;
  }
}

__global__ void k_scan_final(const int* __restrict__ cnt, const int* __restrict__ coff,
                             int* __restrict__ offv) {
  __shared__ int s[SCAN_CH];
  int tid = threadIdx.x;
  int i = blockIdx.x * SCAN_CH + tid;
  int v = (i < N) ? cnt[i] : 0;
  s[tid] = v;
  __syncthreads();
  for (int st = 1; st < SCAN_CH; st <<= 1) {
    int tv = (tid >= st) ? s[tid - st] : 0;
    __syncthreads();
    s[tid] += tv;
    __syncthreads();
  }
  if (i < N) offv[i] = coff[blockIdx.x] + s[tid] - v;   // exclusive
  if (blockIdx.x == 0 && tid == 0) offv[N] = coff[NCH];
}

__global__ void k_fill(const int* __restrict__ row, const int* __restrict__ col,
                       const float* __restrict__ dinv, const int* __restrict__ offv,
                       int* __restrict__ cursor, int* __restrict__ csr_src,
                       float* __restrict__ csr_norm) {
  int e = blockIdx.x * 256 + threadIdx.x;
  if (e >= E) return;
  int r = row[e], c = col[e];
  int p = atomicAdd(&cursor[c], 1);
  int idx = offv[c] + p;
  csr_src[idx]  = r;
  csr_norm[idx] = dinv[r] * dinv[c];
}

// ---------------- weight split/transpose (once per call) ----------------
// LSTM: Bt[j][k] (j<512, k<256): k<128 -> W_ih[j][k], else W_hh[j][k-128]
__global__ void k_wsplit_lstm(const float* __restrict__ Wih, const float* __restrict__ Whh,
                              u16* __restrict__ bhi, u16* __restrict__ blo) {
  int idx = blockIdx.x * 256 + threadIdx.x;   // 512*256
  if (idx >= G * 256) return;
  int j = idx >> 8, k = idx & 255;
  float f = (k < H) ? Wih[j * H + k] : Whh[j * H + (k - H)];
  u16 h = f2bf(f);
  u16 l = f2bf(f - bf2f(h));
  bhi[idx] = h; blo[idx] = l;
}

// GCN: Bt[j][k] = W_gcn[k][j]  (128x128)
__global__ void k_wsplit_gcn(const float* __restrict__ Wg,
                             u16* __restrict__ bhi, u16* __restrict__ blo) {
  int idx = blockIdx.x * 256 + threadIdx.x;   // 128*128
  if (idx >= H * H) return;
  int j = idx >> 7, k = idx & 127;
  float f = Wg[k * H + j];
  u16 h = f2bf(f);
  u16 l = f2bf(f - bf2f(h));
  bhi[idx] = h; blo[idx] = l;
}

// ---------------- GCN GEMM (MFMA): xw = x_t @ W_gcn ----------------
// block 256 thr = 4 waves (2x2) -> 128 rows x 128 cols; K=128 (4 kblocks).
__global__ __launch_bounds__(256) void k_gcn_mfma(const float* __restrict__ X,
                                                  const u16* __restrict__ Bhi,
                                                  const u16* __restrict__ Blo,
                                                  float* __restrict__ xw) {
  int lane = threadIdx.x & 63, wid = threadIdx.x >> 6;
  int wr = wid >> 1, wc = wid & 1;
  int rb = blockIdx.x * 128 + wr * 64;
  int cb = wc * 64;
  int lr = lane & 15;
  int lk = (lane >> 4) * 8;
  f32x4 acc[4][4];
  #pragma unroll
  for (int mi = 0; mi < 4; ++mi)
    #pragma unroll
    for (int ni = 0; ni < 4; ++ni) acc[mi][ni] = (f32x4)0.0f;

  #pragma unroll
  for (int kb = 0; kb < 4; ++kb) {
    int ko = kb * 32 + lk;
    bf16x8 bh[4], bl[4];
    #pragma unroll
    for (int ni = 0; ni < 4; ++ni) {
      size_t off = (size_t)(cb + ni * 16 + lr) * H + ko;
      bh[ni] = *reinterpret_cast<const bf16x8*>(Bhi + off);
      bl[ni] = *reinterpret_cast<const bf16x8*>(Blo + off);
    }
    #pragma unroll
    for (int mi = 0; mi < 4; ++mi) {
      int r = rb + mi * 16 + lr;
      r = r < N ? r : N - 1;                     // clamp (pad rows discarded)
      const float* ap = X + (size_t)r * H + ko;
      float4 a0 = *(const float4*)ap;
      float4 a1 = *(const float4*)(ap + 4);
      float fe[8] = {a0.x, a0.y, a0.z, a0.w, a1.x, a1.y, a1.z, a1.w};
      bf16x8 ah, al;
      #pragma unroll
      for (int e = 0; e < 8; ++e) {
        u16 hh = f2bf(fe[e]);
        ah[e] = (short)hh;
        al[e] = (short)f2bf(fe[e] - bf2f(hh));
      }
      #pragma unroll
      for (int ni = 0; ni < 4; ++ni) {
        acc[mi][ni] = __builtin_amdgcn_mfma_f32_16x16x32_bf16(ah, bh[ni], acc[mi][ni], 0, 0, 0);
        acc[mi][ni] = __builtin_amdgcn_mfma_f32_16x16x32_bf16(ah, bl[ni], acc[mi][ni], 0, 0, 0);
        acc[mi][ni] = __builtin_amdgcn_mfma_f32_16x16x32_bf16(al, bh[ni], acc[mi][ni], 0, 0, 0);
      }
    }
  }
  int orow = (lane >> 4) * 4;
  #pragma unroll
  for (int mi = 0; mi < 4; ++mi)
    #pragma unroll
    for (int ni = 0; ni < 4; ++ni)
      #pragma unroll
      for (int r = 0; r < 4; ++r) {
        int n = rb + mi * 16 + orow + r;
        if (n < N) xw[(size_t)n * H + cb + ni * 16 + lr] = acc[mi][ni][r];
      }
}

// ---------------- aggregation -> emb (bf16 hi/lo planes) ----------------
// Wave per vertex; two 32-lane halves process even/odd edges (float4/lane),
// combined via shfl_xor(32). emb written into Ahi/Alo cols 0..127.
__global__ __launch_bounds__(256) void k_agg(const float* __restrict__ xw,
                                             const int* __restrict__ offv,
                                             const int* __restrict__ csr_src,
                                             const float* __restrict__ csr_norm,
                                             const float* __restrict__ dinv,
                                             const float* __restrict__ bg,
                                             u16* __restrict__ Ahi,
                                             u16* __restrict__ Alo) {
  int wid = threadIdx.x >> 6, lane = threadIdx.x & 63;
  int v = blockIdx.x * 4 + wid;          // N % 4 == 0
  int half = lane >> 5, sl = lane & 31;
  int c0 = sl * 4;
  float ax = 0.f, ay = 0.f, az = 0.f, aw = 0.f;
  if (half == 0) {                       // self term once
    float dv = dinv[v];
    float w = dv * dv;
    float4 xs = *(const float4*)&xw[(size_t)v * H + c0];
    ax = xs.x * w; ay = xs.y * w; az = xs.z * w; aw = xs.w * w;
  }
  int e0 = offv[v], e1 = offv[v + 1];
  for (int e = e0 + half; e < e1; e += 2) {
    int s = csr_src[e]; float m = csr_norm[e];
    float4 x = *(const float4*)&xw[(size_t)s * H + c0];
    ax = fmaf(x.x, m, ax); ay = fmaf(x.y, m, ay);
    az = fmaf(x.z, m, az); aw = fmaf(x.w, m, aw);
  }
  ax += __shfl_xor(ax, 32, 64);
  ay += __shfl_xor(ay, 32, 64);
  az += __shfl_xor(az, 32, 64);
  aw += __shfl_xor(aw, 32, 64);
  float4 bb = *(const float4*)&bg[c0];
  float o0 = fmaxf(ax + bb.x, 0.f), o1 = fmaxf(ay + bb.y, 0.f);
  float o2 = fmaxf(az + bb.z, 0.f), o3 = fmaxf(aw + bb.w, 0.f);
  u16 h0 = f2bf(o0), h1 = f2bf(o1), h2 = f2bf(o2), h3 = f2bf(o3);
  size_t base = (size_t)v * 256 + c0;
  if (half == 0) {
    *(ushort4*)&Ahi[base] = make_ushort4(h0, h1, h2, h3);
  } else {
    u16 l0 = f2bf(o0 - bf2f(h0)), l1 = f2bf(o1 - bf2f(h1));
    u16 l2 = f2bf(o2 - bf2f(h2)), l3 = f2bf(o3 - bf2f(h3));
    *(ushort4*)&Alo[base] = make_ushort4(l0, l1, l2, l3);
  }
}

// ---------------- fused gates GEMM + LSTM cell (LDS-staged) ----------------
// 256 thr = 4 waves (wr x wc = 2x2). Block tile: 128 rows x 128 logical cols,
// where logical col jj = gate*32 + cc maps to global j = gate*128 + colh*32+cc
// -> each wave owns 64 rows x (16 ch x 4 gates): cell update in-register.
// K loop: 8 kblocks of 32; per kblock 32KB (A 16K + B 16K, hi+lo) staged
// global->reg (issued during previous compute) ->LDS; frags via ds_read_b128.
// Grid: 1564 1-D, XCD-chunk swizzled (row-strip's 4 col quarters on one XCD).
template<bool FIRST>
__global__ __launch_bounds__(256) void k_gates_cell(const u16* __restrict__ Ahi,
                                                    const u16* __restrict__ Alo,
                                                    const u16* __restrict__ Bhi,
                                                    const u16* __restrict__ Blo,
                                                    const float* __restrict__ bih,
                                                    const float* __restrict__ bhh,
                                                    float* __restrict__ cbuf,
                                                    float* __restrict__ hbuf,
                                                    u16* __restrict__ oAhi,
                                                    u16* __restrict__ oAlo) {
  __shared__ u16 ls[16384];   // 32KB: [Ahi 4096][Alo 4096][Bhi 4096][Blo 4096]
  const int tid = threadIdx.x;
  const int lane = tid & 63, wid = tid >> 6;
  const int wr = wid >> 1, wc = wid & 1;
  const int lr = lane & 15;
  const int q8 = (lane >> 4) * 8;

  // bijective XCD-chunk swizzle (m204): chunk = contiguous wgids on one XCD
  int xcd = blockIdx.x & 7, loc = blockIdx.x >> 3;
  int wgid = (xcd < GRR ? xcd * (GQQ + 1) : GRR * (GQQ + 1) + (xcd - GRR) * GQQ) + loc;
  const int rb  = (wgid >> 2) * 128;
  const int ch0 = (wgid & 3) * 32;

  f32x4 acc[4][4];
  #pragma unroll
  for (int mi = 0; mi < 4; ++mi)
    #pragma unroll
    for (int ni = 0; ni < 4; ++ni) acc[mi][ni] = (f32x4)0.0f;

  uint4 stg[8];
  auto load_stage = [&](int kb) {
    int ko = kb * 32;
    #pragma unroll
    for (int i = 0; i < 2; ++i) {           // A rows (both planes)
      int flat = i * 256 + tid;
      int row = flat >> 2, q = flat & 3;
      size_t off = (size_t)(rb + row) * 256 + ko + q * 8;
      stg[i]     = *(const uint4*)(Ahi + off);
      stg[i + 2] = *(const uint4*)(Alo + off);
    }
    #pragma unroll
    for (int i = 0; i < 2; ++i) {           // B cols (gate-interleaved)
      int flat = i * 256 + tid;
      int jj = flat >> 2, q = flat & 3;
      int j = (jj >> 5) * 128 + ch0 + (jj & 31);
      size_t off = (size_t)j * 256 + ko + q * 8;
      stg[i + 4] = *(const uint4*)(Bhi + off);
      stg[i + 6] = *(const uint4*)(Blo + off);
    }
  };
  auto write_stage = [&]() {
    #pragma unroll
    for (int i = 0; i < 2; ++i) {
      int flat = i * 256 + tid;
      *(uint4*)&ls[(0 * 512 + flat) * 8] = stg[i];
      *(uint4*)&ls[(1 * 512 + flat) * 8] = stg[i + 2];
      *(uint4*)&ls[(2 * 512 + flat) * 8] = stg[i + 4];
      *(uint4*)&ls[(3 * 512 + flat) * 8] = stg[i + 6];
    }
  };

  const int kbs = FIRST ? 4 : 8;            // t=0: h==0, skip upper K half
  load_stage(0);
  for (int kb = 0; kb < kbs; ++kb) {
    __syncthreads();                        // prev compute done (LDS free)
    write_stage();
    __syncthreads();                        // tile visible
    if (kb + 1 < kbs) load_stage(kb + 1);   // issue next loads under compute
    bf16x8 bh[4], bl[4];
    #pragma unroll
    for (int ni = 0; ni < 4; ++ni) {
      int jj = ni * 32 + wc * 16 + lr;
      bh[ni] = *(const bf16x8*)&ls[8192  + jj * 32 + q8];
      bl[ni] = *(const bf16x8*)&ls[12288 + jj * 32 + q8];
    }
    #pragma unroll
    for (int mi = 0; mi < 4; ++mi) {
      int rr_ = wr * 64 + mi * 16 + lr;
      bf16x8 ah = *(const bf16x8*)&ls[rr_ * 32 + q8];
      bf16x8 al = *(const bf16x8*)&ls[4096 + rr_ * 32 + q8];
      #pragma unroll
      for (int ni = 0; ni < 4; ++ni) {
        acc[mi][ni] = __builtin_amdgcn_mfma_f32_16x16x32_bf16(ah, bh[ni], acc[mi][ni], 0, 0, 0);
        acc[mi][ni] = __builtin_amdgcn_mfma_f32_16x16x32_bf16(ah, bl[ni], acc[mi][ni], 0, 0, 0);
        acc[mi][ni] = __builtin_amdgcn_mfma_f32_16x16x32_bf16(al, bh[ni], acc[mi][ni], 0, 0, 0);
      }
    }
  }

  int ch = ch0 + wc * 16 + lr;
  float bi_ = bih[ch]       + bhh[ch];
  float bf_ = bih[128 + ch] + bhh[128 + ch];
  float bg_ = bih[256 + ch] + bhh[256 + ch];
  float bo_ = bih[384 + ch] + bhh[384 + ch];
  int orow = (lane >> 4) * 4;
  int rbw = rb + wr * 64;
  #pragma unroll
  for (int mi = 0; mi < 4; ++mi) {
    #pragma unroll
    for (int r = 0; r < 4; ++r) {
      int n = rbw + mi * 16 + orow + r;
      if (n >= N) continue;
      float gi = acc[mi][0][r] + bi_;
      float gf = acc[mi][1][r] + bf_;
      float gg = acc[mi][2][r] + bg_;
      float go = acc[mi][3][r] + bo_;
      float si = 1.f / (1.f + expf(-gi));
      float sf = 1.f / (1.f + expf(-gf));
      float so = 1.f / (1.f + expf(-go));
      float tg = tanhf(gg);
      size_t ci = (size_t)n * H + ch;
      float cn = FIRST ? si * tg : fmaf(sf, cbuf[ci], si * tg);
      cbuf[ci] = cn;
      float hn = so * tanhf(cn);
      hbuf[ci] = hn;
      u16 hv = f2bf(hn);
      size_t ab = (size_t)n * 256 + 128 + ch;
      oAhi[ab] = hv;
      oAlo[ab] = f2bf(hn - bf2f(hv));
    }
  }
}

// ---------------- FC per step: out[n][t][:] = h[n] @ W_fc^T + b_fc ----------------
__global__ __launch_bounds__(256, 3) void k_fc(const float* __restrict__ h,
                                               const float* __restrict__ Wfc,
                                               const float* __restrict__ bfc,
                                               float* __restrict__ outp, int t) {
  __shared__ float hsT[128][68];
  __shared__ float wT[128][36];
  int tid = threadIdx.x;
  int n0 = blockIdx.x * 64;
  for (int i = 0; i < 32; ++i) {
    int idx = i * 256 + tid;
    int r = idx >> 7, k = idx & 127;
    hsT[k][r] = (n0 + r < N) ? h[(size_t)(n0 + r) * H + k] : 0.0f;
  }
  for (int i = 0; i < 16; ++i) {
    int idx = i * 256 + tid;          // 4096 = 32*128
    int oc = idx >> 7, k = idx & 127;
    wT[k][oc] = Wfc[idx];
  }
  __syncthreads();
  int og = tid & 15, rg = tid >> 4;   // 16 oc-groups x 16 row-groups
  int oc0 = og * 2, r0 = rg * 4;
  float acc[4][2] = {};
  #pragma unroll 2
  for (int k = 0; k < 128; ++k) {
    float4 a = *(const float4*)&hsT[k][r0];
    float2 w = *(const float2*)&wT[k][oc0];
    float ar[4] = {a.x, a.y, a.z, a.w};
    #pragma unroll
    for (int i = 0; i < 4; ++i) {
      acc[i][0] = fmaf(ar[i], w.x, acc[i][0]);
      acc[i][1] = fmaf(ar[i], w.y, acc[i][1]);
    }
  }
  float b0 = bfc[oc0], b1 = bfc[oc0 + 1];
  #pragma unroll
  for (int i = 0; i < 4; ++i) {
    int n = n0 + r0 + i;
    if (n < N) {
      size_t ob = ((size_t)n * T + t) * OUTD + oc0;
      outp[ob]     = acc[i][0] + b0;
      outp[ob + 1] = acc[i][1] + b1;
    }
  }
}

// ---------------------------------------------------------------------------

extern "C" void kernel_launch(void* const* d_in, const int* in_sizes, int n_in,
                              void* d_out, int out_size, void* d_ws, size_t ws_size,
                              hipStream_t stream) {
  const float* x_seq = (const float*)d_in[0];
  const int*   eidx  = (const int*)d_in[1];
  const int*   erow  = eidx;          // sources
  const int*   ecol  = eidx + E;      // targets
  const float* W_gcn = (const float*)d_in[2];
  const float* b_gcn = (const float*)d_in[3];
  const float* W_ih  = (const float*)d_in[4];
  const float* W_hh  = (const float*)d_in[5];
  const float* b_ih  = (const float*)d_in[6];
  const float* b_hh  = (const float*)d_in[7];
  const float* W_fc  = (const float*)d_in[8];
  const float* b_fc  = (const float*)d_in[9];
  float* outp = (float*)d_out;

  char* base = (char*)d_ws;
  size_t o = 0;
  auto alloc = [&](size_t bytes) -> void* {
    void* p = base + o;
    o += (bytes + 255) & ~(size_t)255;
    return p;
  };
  int*   cnt      = (int*)  alloc((size_t)N * 4);
  int*   cursor   = (int*)  alloc((size_t)N * 4);
  int*   offv     = (int*)  alloc((size_t)(N + 1) * 4);
  int*   csum     = (int*)  alloc((size_t)(NCH + 1) * 4);
  int*   coff     = (int*)  alloc((size_t)(NCH + 1) * 4);
  float* dinv     = (float*)alloc((size_t)N * 4);
  int*   csr_src  = (int*)  alloc((size_t)E * 4);
  float* csr_norm = (float*)alloc((size_t)E * 4);
  u16*   bt_hi    = (u16*)  alloc((size_t)G * 256 * 2);
  u16*   bt_lo    = (u16*)  alloc((size_t)G * 256 * 2);
  u16*   bg_hi    = (u16*)  alloc((size_t)H * H * 2);
  u16*   bg_lo    = (u16*)  alloc((size_t)H * H * 2);
  u16*   a_hi0    = (u16*)  alloc((size_t)NP * 256 * 2);   // [emb | h] bf16-hi, even t
  u16*   a_lo0    = (u16*)  alloc((size_t)NP * 256 * 2);
  u16*   a_hi1    = (u16*)  alloc((size_t)NP * 256 * 2);   // odd t
  u16*   a_lo1    = (u16*)  alloc((size_t)NP * 256 * 2);
  float* xw       = (float*)alloc((size_t)N * H * 4);
  float* hbuf     = (float*)alloc((size_t)N * H * 4);
  float* cbuf     = (float*)alloc((size_t)N * H * 4);
  (void)ws_size; (void)in_sizes; (void)n_in; (void)out_size;

  u16* AHI[2] = {a_hi0, a_hi1};
  u16* ALO[2] = {a_lo0, a_lo1};

  // only the small CSR counters need zeroing; h/c state handled by the
  // FIRST-step specialization; pad rows only affect discarded output rows.
  hipMemsetAsync(cnt,    0, (size_t)N * 4, stream);
  hipMemsetAsync(cursor, 0, (size_t)N * 4, stream);

  k_count<<<E / 256, 256, 0, stream>>>(ecol, cnt);
  k_dinv<<<(N + 255) / 256, 256, 0, stream>>>(cnt, dinv);
  k_chunk_sum<<<NCH, SCAN_CH, 0, stream>>>(cnt, csum);
  k_chunk_scan<<<1, 64, 0, stream>>>(csum, coff);
  k_scan_final<<<NCH, SCAN_CH, 0, stream>>>(cnt, coff, offv);
  k_fill<<<E / 256, 256, 0, stream>>>(erow, ecol, dinv, offv, cursor, csr_src, csr_norm);
  k_wsplit_lstm<<<(G * 256) / 256, 256, 0, stream>>>(W_ih, W_hh, bt_hi, bt_lo);
  k_wsplit_gcn<<<(H * H) / 256, 256, 0, stream>>>(W_gcn, bg_hi, bg_lo);

  int gblocks = NP / 128;                 // 391, for k_gcn_mfma
  int rblocks = (N + 63) / 64;            // for k_fc
  for (int t = 0; t < T; ++t) {
    int cur = t & 1, nxt = cur ^ 1;
    const float* xt = x_seq + (size_t)t * N * H;
    k_gcn_mfma<<<gblocks, 256, 0, stream>>>(xt, bg_hi, bg_lo, xw);
    k_agg<<<N / 4, 256, 0, stream>>>(xw, offv, csr_src, csr_norm, dinv, b_gcn,
                                     AHI[cur], ALO[cur]);
    if (t == 0)
      k_gates_cell<true><<<GNWG, 256, 0, stream>>>(
          AHI[cur], ALO[cur], bt_hi, bt_lo, b_ih, b_hh, cbuf, hbuf, AHI[nxt], ALO[nxt]);
    else
      k_gates_cell<false><<<GNWG, 256, 0, stream>>>(
          AHI[cur], ALO[cur], bt_hi, bt_lo, b_ih, b_hh, cbuf, hbuf, AHI[nxt], ALO[nxt]);
    k_fc<<<rblocks, 256, 0, stream>>>(hbuf, W_fc, b_fc, outp, t);
  }
}

// Round 7
// 2339.832 us; speedup vs baseline: 1.3678x; 1.3172x over previous
//
#include <hip/hip_runtime.h>
#include <cstdint>
#include <cstddef>

// ---------------------------------------------------------------------------
// GCN(1 layer, sym-norm w/ self loops) -> LSTM(1 layer, T=9) -> FC, eval mode
// Round 7: k_gates_cell staged via __builtin_amdgcn_global_load_lds (no data
// registers -> no scratch spill), kblock=32 double-buffered 64KB LDS,
// pair-row XOR-swizzled layout (conflict-free ds_read_b128) applied by
// pre-swizzling the GLOBAL source address (LDS writes stay linear).
// ---------------------------------------------------------------------------

constexpr int N    = 50000;
constexpr int NP   = 50048;  // padded to 128-row strips (391*128)
constexpr int E    = 1600000;
constexpr int T    = 9;
constexpr int H    = 128;    // F_IN == H == 128
constexpr int G    = 512;    // 4*H (gates i,f,g,o)
constexpr int OUTD = 32;

constexpr int SCAN_CH = 512;
constexpr int NCH = (N + SCAN_CH - 1) / SCAN_CH;   // 98

// gates grid: 391 row-strips x 4 col-quarters
constexpr int GNWG = (NP / 128) * 4;               // 1564
constexpr int GQQ  = GNWG / 8;                     // 195
constexpr int GRR  = GNWG % 8;                     // 4

typedef __attribute__((ext_vector_type(8))) short bf16x8;
typedef __attribute__((ext_vector_type(4))) float f32x4;
typedef unsigned short u16;

__device__ __forceinline__ u16 f2bf(float f) {        // RNE f32 -> bf16 bits
  unsigned u = __builtin_bit_cast(unsigned, f);
  u += 0x7fffu + ((u >> 16) & 1u);
  return (u16)(u >> 16);
}
__device__ __forceinline__ float bf2f(u16 h) {
  unsigned u = ((unsigned)h) << 16;
  return __builtin_bit_cast(float, u);
}

// async global->LDS, 16B per lane; LDS dest = wave-uniform base + lane*16
__device__ __forceinline__ void gll16(const u16* g, u16* l) {
  __builtin_amdgcn_global_load_lds(
      (const __attribute__((address_space(1))) void*)g,
      (__attribute__((address_space(3))) void*)l, 16, 0, 0);
}

// ---------------- degree / CSR build ----------------

__global__ void k_count(const int* __restrict__ col, int* __restrict__ cnt) {
  int e = blockIdx.x * 256 + threadIdx.x;
  if (e < E) atomicAdd(&cnt[col[e]], 1);
}

__global__ void k_dinv(const int* __restrict__ cnt, float* __restrict__ dinv) {
  int v = blockIdx.x * 256 + threadIdx.x;
  if (v < N) dinv[v] = rsqrtf((float)cnt[v] + 1.0f);   // +1 self loop
}

__global__ void k_chunk_sum(const int* __restrict__ cnt, int* __restrict__ csum) {
  __shared__ int sp[SCAN_CH / 64];
  int i = blockIdx.x * SCAN_CH + threadIdx.x;
  int v = (i < N) ? cnt[i] : 0;
  for (int off = 32; off > 0; off >>= 1) v += __shfl_down(v, off, 64);
  if ((threadIdx.x & 63) == 0) sp[threadIdx.x >> 6] = v;
  __syncthreads();
  if (threadIdx.x == 0) {
    int s = 0;
    #pragma unroll
    for (int w = 0; w < SCAN_CH / 64; ++w) s += sp[w];
    csum[blockIdx.x] = s;
  }
}

__global__ void k_chunk_scan(const int* __restrict__ csum, int* __restrict__ coff) {
  if (blockIdx.x == 0 && threadIdx.x == 0) {
    int run = 0;
    for (int b = 0; b < NCH; ++b) { coff[b] = run; run += csum[b]; }
    coff[NCH] = run;
  }
}

__global__ void k_scan_final(const int* __restrict__ cnt, const int* __restrict__ coff,
                             int* __restrict__ offv) {
  __shared__ int s[SCAN_CH];
  int tid = threadIdx.x;
  int i = blockIdx.x * SCAN_CH + tid;
  int v = (i < N) ? cnt[i] : 0;
  s[tid] = v;
  __syncthreads();
  for (int st = 1; st < SCAN_CH; st <<= 1) {
    int tv = (tid >= st) ? s[tid - st] : 0;
    __syncthreads();
    s[tid] += tv;
    __syncthreads();
  }
  if (i < N) offv[i] = coff[blockIdx.x] + s[tid] - v;   // exclusive
  if (blockIdx.x == 0 && tid == 0) offv[N] = coff[NCH];
}

__global__ void k_fill(const int* __restrict__ row, const int* __restrict__ col,
                       const float* __restrict__ dinv, const int* __restrict__ offv,
                       int* __restrict__ cursor, int* __restrict__ csr_src,
                       float* __restrict__ csr_norm) {
  int e = blockIdx.x * 256 + threadIdx.x;
  if (e >= E) return;
  int r = row[e], c = col[e];
  int p = atomicAdd(&cursor[c], 1);
  int idx = offv[c] + p;
  csr_src[idx]  = r;
  csr_norm[idx] = dinv[r] * dinv[c];
}

// ---------------- weight split/transpose (once per call) ----------------
// LSTM: Bt[j][k] (j<512, k<256): k<128 -> W_ih[j][k], else W_hh[j][k-128]
__global__ void k_wsplit_lstm(const float* __restrict__ Wih, const float* __restrict__ Whh,
                              u16* __restrict__ bhi, u16* __restrict__ blo) {
  int idx = blockIdx.x * 256 + threadIdx.x;   // 512*256
  if (idx >= G * 256) return;
  int j = idx >> 8, k = idx & 255;
  float f = (k < H) ? Wih[j * H + k] : Whh[j * H + (k - H)];
  u16 h = f2bf(f);
  u16 l = f2bf(f - bf2f(h));
  bhi[idx] = h; blo[idx] = l;
}

// GCN: Bt[j][k] = W_gcn[k][j]  (128x128)
__global__ void k_wsplit_gcn(const float* __restrict__ Wg,
                             u16* __restrict__ bhi, u16* __restrict__ blo) {
  int idx = blockIdx.x * 256 + threadIdx.x;   // 128*128
  if (idx >= H * H) return;
  int j = idx >> 7, k = idx & 127;
  float f = Wg[k * H + j];
  u16 h = f2bf(f);
  u16 l = f2bf(f - bf2f(h));
  bhi[idx] = h; blo[idx] = l;
}

// ---------------- GCN GEMM (MFMA): xw = x_t @ W_gcn ----------------
// block 256 thr = 4 waves (2x2) -> 128 rows x 128 cols; K=128 (4 kblocks).
__global__ __launch_bounds__(256) void k_gcn_mfma(const float* __restrict__ X,
                                                  const u16* __restrict__ Bhi,
                                                  const u16* __restrict__ Blo,
                                                  float* __restrict__ xw) {
  int lane = threadIdx.x & 63, wid = threadIdx.x >> 6;
  int wr = wid >> 1, wc = wid & 1;
  int rb = blockIdx.x * 128 + wr * 64;
  int cb = wc * 64;
  int lr = lane & 15;
  int lk = (lane >> 4) * 8;
  f32x4 acc[4][4];
  #pragma unroll
  for (int mi = 0; mi < 4; ++mi)
    #pragma unroll
    for (int ni = 0; ni < 4; ++ni) acc[mi][ni] = (f32x4)0.0f;

  #pragma unroll
  for (int kb = 0; kb < 4; ++kb) {
    int ko = kb * 32 + lk;
    bf16x8 bh[4], bl[4];
    #pragma unroll
    for (int ni = 0; ni < 4; ++ni) {
      size_t off = (size_t)(cb + ni * 16 + lr) * H + ko;
      bh[ni] = *reinterpret_cast<const bf16x8*>(Bhi + off);
      bl[ni] = *reinterpret_cast<const bf16x8*>(Blo + off);
    }
    #pragma unroll
    for (int mi = 0; mi < 4; ++mi) {
      int r = rb + mi * 16 + lr;
      r = r < N ? r : N - 1;                     // clamp (pad rows discarded)
      const float* ap = X + (size_t)r * H + ko;
      float4 a0 = *(const float4*)ap;
      float4 a1 = *(const float4*)(ap + 4);
      float fe[8] = {a0.x, a0.y, a0.z, a0.w, a1.x, a1.y, a1.z, a1.w};
      bf16x8 ah, al;
      #pragma unroll
      for (int e = 0; e < 8; ++e) {
        u16 hh = f2bf(fe[e]);
        ah[e] = (short)hh;
        al[e] = (short)f2bf(fe[e] - bf2f(hh));
      }
      #pragma unroll
      for (int ni = 0; ni < 4; ++ni) {
        acc[mi][ni] = __builtin_amdgcn_mfma_f32_16x16x32_bf16(ah, bh[ni], acc[mi][ni], 0, 0, 0);
        acc[mi][ni] = __builtin_amdgcn_mfma_f32_16x16x32_bf16(ah, bl[ni], acc[mi][ni], 0, 0, 0);
        acc[mi][ni] = __builtin_amdgcn_mfma_f32_16x16x32_bf16(al, bh[ni], acc[mi][ni], 0, 0, 0);
      }
    }
  }
  int orow = (lane >> 4) * 4;
  #pragma unroll
  for (int mi = 0; mi < 4; ++mi)
    #pragma unroll
    for (int ni = 0; ni < 4; ++ni)
      #pragma unroll
      for (int r = 0; r < 4; ++r) {
        int n = rb + mi * 16 + orow + r;
        if (n < N) xw[(size_t)n * H + cb + ni * 16 + lr] = acc[mi][ni][r];
      }
}

// ---------------- aggregation -> emb (bf16 hi/lo planes) ----------------
// Wave per vertex; two 32-lane halves process even/odd edges (float4/lane),
// combined via shfl_xor(32). emb written into Ahi/Alo cols 0..127.
__global__ __launch_bounds__(256) void k_agg(const float* __restrict__ xw,
                                             const int* __restrict__ offv,
                                             const int* __restrict__ csr_src,
                                             const float* __restrict__ csr_norm,
                                             const float* __restrict__ dinv,
                                             const float* __restrict__ bg,
                                             u16* __restrict__ Ahi,
                                             u16* __restrict__ Alo) {
  int wid = threadIdx.x >> 6, lane = threadIdx.x & 63;
  int v = blockIdx.x * 4 + wid;          // N % 4 == 0
  int half = lane >> 5, sl = lane & 31;
  int c0 = sl * 4;
  float ax = 0.f, ay = 0.f, az = 0.f, aw = 0.f;
  if (half == 0) {                       // self term once
    float dv = dinv[v];
    float w = dv * dv;
    float4 xs = *(const float4*)&xw[(size_t)v * H + c0];
    ax = xs.x * w; ay = xs.y * w; az = xs.z * w; aw = xs.w * w;
  }
  int e0 = offv[v], e1 = offv[v + 1];
  for (int e = e0 + half; e < e1; e += 2) {
    int s = csr_src[e]; float m = csr_norm[e];
    float4 x = *(const float4*)&xw[(size_t)s * H + c0];
    ax = fmaf(x.x, m, ax); ay = fmaf(x.y, m, ay);
    az = fmaf(x.z, m, az); aw = fmaf(x.w, m, aw);
  }
  ax += __shfl_xor(ax, 32, 64);
  ay += __shfl_xor(ay, 32, 64);
  az += __shfl_xor(az, 32, 64);
  aw += __shfl_xor(aw, 32, 64);
  float4 bb = *(const float4*)&bg[c0];
  float o0 = fmaxf(ax + bb.x, 0.f), o1 = fmaxf(ay + bb.y, 0.f);
  float o2 = fmaxf(az + bb.z, 0.f), o3 = fmaxf(aw + bb.w, 0.f);
  u16 h0 = f2bf(o0), h1 = f2bf(o1), h2 = f2bf(o2), h3 = f2bf(o3);
  size_t base = (size_t)v * 256 + c0;
  if (half == 0) {
    *(ushort4*)&Ahi[base] = make_ushort4(h0, h1, h2, h3);
  } else {
    u16 l0 = f2bf(o0 - bf2f(h0)), l1 = f2bf(o1 - bf2f(h1));
    u16 l2 = f2bf(o2 - bf2f(h2)), l3 = f2bf(o3 - bf2f(h3));
    *(ushort4*)&Alo[base] = make_ushort4(l0, l1, l2, l3);
  }
}

// ---------------- fused gates GEMM + LSTM cell (global_load_lds staged) ------
// 256 thr = 4 waves (wr x wc = 2x2). Block tile: 128 rows x 128 logical cols
// (jj = gate*32 + wc*16 + lr -> global j = gate*128 + ch0 + ...), so each wave
// holds (i,f,g,o) of the same (row, channel): cell update in-register.
// K: 8 kblocks of 32, double-buffered 2x32KB LDS staged by global_load_lds
// (16B/lane, LDS linear). Swizzle: tile = 64 row-pairs x 128B; granule
// g3=(row&1)*4+q stored at slot g3^(pair&7) -> ds_read_b128 is 2-way (free).
// Swizzle applied by PRE-SWIZZLING the global source address (rule #21).
template<bool FIRST>
__global__ __launch_bounds__(256) void k_gates_cell(const u16* __restrict__ Ahi,
                                                    const u16* __restrict__ Alo,
                                                    const u16* __restrict__ Bhi,
                                                    const u16* __restrict__ Blo,
                                                    const float* __restrict__ bih,
                                                    const float* __restrict__ bhh,
                                                    float* __restrict__ cbuf,
                                                    float* __restrict__ hbuf,
                                                    u16* __restrict__ oAhi,
                                                    u16* __restrict__ oAlo) {
  __shared__ u16 ls[2][16384];   // 2 x 32KB: [Ahi 8K][Alo 8K][Bhi 8K][Blo 8K]
  const int tid = threadIdx.x;
  const int lane = tid & 63, wid = tid >> 6;
  const int wr = wid >> 1, wc = wid & 1;
  const int lr = lane & 15;
  const int g  = lane >> 4;                 // k granule 0..3 (8 bf16 each)

  // bijective XCD-chunk swizzle (m204)
  int xcd = blockIdx.x & 7, loc = blockIdx.x >> 3;
  int wgid = (xcd < GRR ? xcd * (GQQ + 1) : GRR * (GQQ + 1) + (xcd - GRR) * GQQ) + loc;
  const int rb  = (wgid >> 2) * 128;
  const int ch0 = (wgid & 3) * 32;

  f32x4 acc[4][4];
  #pragma unroll
  for (int mi = 0; mi < 4; ++mi)
    #pragma unroll
    for (int ni = 0; ni < 4; ++ni) acc[mi][ni] = (f32x4)0.0f;

  // stage one 32KB k-block tile (async, no data registers)
  auto stage = [&](int buf, int kb) {
    int ko = kb * 32;
    u16* lb = &ls[buf][0];
    #pragma unroll
    for (int i = 0; i < 2; ++i) {
      int c = i * 256 + tid;               // 16B chunk id 0..511 per section
      int p = c >> 3, gs = c & 7;
      int g3 = gs ^ (p & 7);               // pre-swizzled global granule
      int row = p * 2 + (g3 >> 2);
      int q = g3 & 3;
      size_t ga = (size_t)(rb + row) * 256 + ko + q * 8;
      gll16(Ahi + ga, lb + c * 8);
      gll16(Alo + ga, lb + 4096 + c * 8);
      int j = (row >> 5) * 128 + ch0 + (row & 31);
      size_t gb = (size_t)j * 256 + ko + q * 8;
      gll16(Bhi + gb, lb + 8192 + c * 8);
      gll16(Blo + gb, lb + 12288 + c * 8);
    }
  };

  auto compute = [&](int buf) {
    const u16* lb = &ls[buf][0];
    bf16x8 bh[4], bl[4];
    #pragma unroll
    for (int ni = 0; ni < 4; ++ni) {
      int jj = ni * 32 + wc * 16 + lr;
      int p = jj >> 1;
      int g3 = ((jj & 1) << 2) | g;
      int off = p * 64 + (g3 ^ (p & 7)) * 8;
      bh[ni] = *(const bf16x8*)(lb + 8192 + off);
      bl[ni] = *(const bf16x8*)(lb + 12288 + off);
    }
    #pragma unroll
    for (int mi = 0; mi < 4; ++mi) {
      int rr = wr * 64 + mi * 16 + lr;
      int p = rr >> 1;
      int g3 = ((rr & 1) << 2) | g;
      int off = p * 64 + (g3 ^ (p & 7)) * 8;
      bf16x8 ah = *(const bf16x8*)(lb + off);
      bf16x8 al = *(const bf16x8*)(lb + 4096 + off);
      #pragma unroll
      for (int ni = 0; ni < 4; ++ni) {
        acc[mi][ni] = __builtin_amdgcn_mfma_f32_16x16x32_bf16(ah, bh[ni], acc[mi][ni], 0, 0, 0);
        acc[mi][ni] = __builtin_amdgcn_mfma_f32_16x16x32_bf16(ah, bl[ni], acc[mi][ni], 0, 0, 0);
        acc[mi][ni] = __builtin_amdgcn_mfma_f32_16x16x32_bf16(al, bh[ni], acc[mi][ni], 0, 0, 0);
      }
    }
  };

  const int kbs = FIRST ? 4 : 8;            // t=0: h==0, skip upper K half
  stage(0, 0);
  for (int kb = 0; kb < kbs; ++kb) {
    __syncthreads();                        // buf[kb&1] staged; prev reads done
    if (kb + 1 < kbs) stage((kb + 1) & 1, kb + 1);  // async, hides under MFMAs
    compute(kb & 1);
  }

  int ch = ch0 + wc * 16 + lr;
  float bi_ = bih[ch]       + bhh[ch];
  float bf_ = bih[128 + ch] + bhh[128 + ch];
  float bg_ = bih[256 + ch] + bhh[256 + ch];
  float bo_ = bih[384 + ch] + bhh[384 + ch];
  int orow = (lane >> 4) * 4;
  int rbw = rb + wr * 64;
  #pragma unroll
  for (int mi = 0; mi < 4; ++mi) {
    #pragma unroll
    for (int r = 0; r < 4; ++r) {
      int n = rbw + mi * 16 + orow + r;
      if (n >= N) continue;
      float gi = acc[mi][0][r] + bi_;
      float gf = acc[mi][1][r] + bf_;
      float gg = acc[mi][2][r] + bg_;
      float go = acc[mi][3][r] + bo_;
      float si = 1.f / (1.f + expf(-gi));
      float sf = 1.f / (1.f + expf(-gf));
      float so = 1.f / (1.f + expf(-go));
      float tg = tanhf(gg);
      size_t ci = (size_t)n * H + ch;
      float cn = FIRST ? si * tg : fmaf(sf, cbuf[ci], si * tg);
      cbuf[ci] = cn;
      float hn = so * tanhf(cn);
      hbuf[ci] = hn;
      u16 hv = f2bf(hn);
      size_t ab = (size_t)n * 256 + 128 + ch;
      oAhi[ab] = hv;
      oAlo[ab] = f2bf(hn - bf2f(hv));
    }
  }
}

// ---------------- FC per step: out[n][t][:] = h[n] @ W_fc^T + b_fc ----------------
__global__ __launch_bounds__(256, 3) void k_fc(const float* __restrict__ h,
                                               const float* __restrict__ Wfc,
                                               const float* __restrict__ bfc,
                                               float* __restrict__ outp, int t) {
  __shared__ float hsT[128][68];
  __shared__ float wT[128][36];
  int tid = threadIdx.x;
  int n0 = blockIdx.x * 64;
  for (int i = 0; i < 32; ++i) {
    int idx = i * 256 + tid;
    int r = idx >> 7, k = idx & 127;
    hsT[k][r] = (n0 + r < N) ? h[(size_t)(n0 + r) * H + k] : 0.0f;
  }
  for (int i = 0; i < 16; ++i) {
    int idx = i * 256 + tid;          // 4096 = 32*128
    int oc = idx >> 7, k = idx & 127;
    wT[k][oc] = Wfc[idx];
  }
  __syncthreads();
  int og = tid & 15, rg = tid >> 4;   // 16 oc-groups x 16 row-groups
  int oc0 = og * 2, r0 = rg * 4;
  float acc[4][2] = {};
  #pragma unroll 2
  for (int k = 0; k < 128; ++k) {
    float4 a = *(const float4*)&hsT[k][r0];
    float2 w = *(const float2*)&wT[k][oc0];
    float ar[4] = {a.x, a.y, a.z, a.w};
    #pragma unroll
    for (int i = 0; i < 4; ++i) {
      acc[i][0] = fmaf(ar[i], w.x, acc[i][0]);
      acc[i][1] = fmaf(ar[i], w.y, acc[i][1]);
    }
  }
  float b0 = bfc[oc0], b1 = bfc[oc0 + 1];
  #pragma unroll
  for (int i = 0; i < 4; ++i) {
    int n = n0 + r0 + i;
    if (n < N) {
      size_t ob = ((size_t)n * T + t) * OUTD + oc0;
      outp[ob]     = acc[i][0] + b0;
      outp[ob + 1] = acc[i][1] + b1;
    }
  }
}

// ---------------------------------------------------------------------------

extern "C" void kernel_launch(void* const* d_in, const int* in_sizes, int n_in,
                              void* d_out, int out_size, void* d_ws, size_t ws_size,
                              hipStream_t stream) {
  const float* x_seq = (const float*)d_in[0];
  const int*   eidx  = (const int*)d_in[1];
  const int*   erow  = eidx;          // sources
  const int*   ecol  = eidx + E;      // targets
  const float* W_gcn = (const float*)d_in[2];
  const float* b_gcn = (const float*)d_in[3];
  const float* W_ih  = (const float*)d_in[4];
  const float* W_hh  = (const float*)d_in[5];
  const float* b_ih  = (const float*)d_in[6];
  const float* b_hh  = (const float*)d_in[7];
  const float* W_fc  = (const float*)d_in[8];
  const float* b_fc  = (const float*)d_in[9];
  float* outp = (float*)d_out;

  char* base = (char*)d_ws;
  size_t o = 0;
  auto alloc = [&](size_t bytes) -> void* {
    void* p = base + o;
    o += (bytes + 255) & ~(size_t)255;
    return p;
  };
  int*   cnt      = (int*)  alloc((size_t)N * 4);
  int*   cursor   = (int*)  alloc((size_t)N * 4);
  int*   offv     = (int*)  alloc((size_t)(N + 1) * 4);
  int*   csum     = (int*)  alloc((size_t)(NCH + 1) * 4);
  int*   coff     = (int*)  alloc((size_t)(NCH + 1) * 4);
  float* dinv     = (float*)alloc((size_t)N * 4);
  int*   csr_src  = (int*)  alloc((size_t)E * 4);
  float* csr_norm = (float*)alloc((size_t)E * 4);
  u16*   bt_hi    = (u16*)  alloc((size_t)G * 256 * 2);
  u16*   bt_lo    = (u16*)  alloc((size_t)G * 256 * 2);
  u16*   bg_hi    = (u16*)  alloc((size_t)H * H * 2);
  u16*   bg_lo    = (u16*)  alloc((size_t)H * H * 2);
  u16*   a_hi0    = (u16*)  alloc((size_t)NP * 256 * 2);   // [emb | h] bf16-hi, even t
  u16*   a_lo0    = (u16*)  alloc((size_t)NP * 256 * 2);
  u16*   a_hi1    = (u16*)  alloc((size_t)NP * 256 * 2);   // odd t
  u16*   a_lo1    = (u16*)  alloc((size_t)NP * 256 * 2);
  float* xw       = (float*)alloc((size_t)N * H * 4);
  float* hbuf     = (float*)alloc((size_t)N * H * 4);
  float* cbuf     = (float*)alloc((size_t)N * H * 4);
  (void)ws_size; (void)in_sizes; (void)n_in; (void)out_size;

  u16* AHI[2] = {a_hi0, a_hi1};
  u16* ALO[2] = {a_lo0, a_lo1};

  // only the small CSR counters need zeroing; h/c state handled by the
  // FIRST-step specialization; pad rows only affect discarded output rows.
  hipMemsetAsync(cnt,    0, (size_t)N * 4, stream);
  hipMemsetAsync(cursor, 0, (size_t)N * 4, stream);

  k_count<<<E / 256, 256, 0, stream>>>(ecol, cnt);
  k_dinv<<<(N + 255) / 256, 256, 0, stream>>>(cnt, dinv);
  k_chunk_sum<<<NCH, SCAN_CH, 0, stream>>>(cnt, csum);
  k_chunk_scan<<<1, 64, 0, stream>>>(csum, coff);
  k_scan_final<<<NCH, SCAN_CH, 0, stream>>>(cnt, coff, offv);
  k_fill<<<E / 256, 256, 0, stream>>>(erow, ecol, dinv, offv, cursor, csr_src, csr_norm);
  k_wsplit_lstm<<<(G * 256) / 256, 256, 0, stream>>>(W_ih, W_hh, bt_hi, bt_lo);
  k_wsplit_gcn<<<(H * H) / 256, 256, 0, stream>>>(W_gcn, bg_hi, bg_lo);

  int gblocks = NP / 128;                 // 391, for k_gcn_mfma
  int rblocks = (N + 63) / 64;            // for k_fc
  for (int t = 0; t < T; ++t) {
    int cur = t & 1, nxt = cur ^ 1;
    const float* xt = x_seq + (size_t)t * N * H;
    k_gcn_mfma<<<gblocks, 256, 0, stream>>>(xt, bg_hi, bg_lo, xw);
    k_agg<<<N / 4, 256, 0, stream>>>(xw, offv, csr_src, csr_norm, dinv, b_gcn,
                                     AHI[cur], ALO[cur]);
    if (t == 0)
      k_gates_cell<true><<<GNWG, 256, 0, stream>>>(
          AHI[cur], ALO[cur], bt_hi, bt_lo, b_ih, b_hh, cbuf, hbuf, AHI[nxt], ALO[nxt]);
    else
      k_gates_cell<false><<<GNWG, 256, 0, stream>>>(
          AHI[cur], ALO[cur], bt_hi, bt_lo, b_ih, b_hh, cbuf, hbuf, AHI[nxt], ALO[nxt]);
    k_fc<<<rblocks, 256, 0, stream>>>(hbuf, W_fc, b_fc, outp, t);
  }
}

// Round 8
// 2131.251 us; speedup vs baseline: 1.5017x; 1.0979x over previous
//
#include <hip/hip_runtime.h>
#include <cstdint>
#include <cstddef>

// ---------------------------------------------------------------------------
// GCN(1 layer, sym-norm w/ self loops) -> LSTM(1 layer, T=9) -> FC, eval mode
// Round 8: xw buffer moved to fp16 (gather traffic halved; agg is L3-BW-bound
// at E*rowbytes). GCN epilogue writes fp16; agg gathers f16x4 and accumulates
// fp32. Gates kernel (global_load_lds staged) unchanged from round 7.
// ---------------------------------------------------------------------------

constexpr int N    = 50000;
constexpr int NP   = 50048;  // padded to 128-row strips (391*128)
constexpr int E    = 1600000;
constexpr int T    = 9;
constexpr int H    = 128;    // F_IN == H == 128
constexpr int G    = 512;    // 4*H (gates i,f,g,o)
constexpr int OUTD = 32;

constexpr int SCAN_CH = 512;
constexpr int NCH = (N + SCAN_CH - 1) / SCAN_CH;   // 98

// gates grid: 391 row-strips x 4 col-quarters
constexpr int GNWG = (NP / 128) * 4;               // 1564
constexpr int GQQ  = GNWG / 8;                     // 195
constexpr int GRR  = GNWG % 8;                     // 4

typedef __attribute__((ext_vector_type(8))) short bf16x8;
typedef __attribute__((ext_vector_type(4))) float f32x4;
typedef __attribute__((ext_vector_type(4))) _Float16 f16x4;
typedef unsigned short u16;

__device__ __forceinline__ u16 f2bf(float f) {        // RNE f32 -> bf16 bits
  unsigned u = __builtin_bit_cast(unsigned, f);
  u += 0x7fffu + ((u >> 16) & 1u);
  return (u16)(u >> 16);
}
__device__ __forceinline__ float bf2f(u16 h) {
  unsigned u = ((unsigned)h) << 16;
  return __builtin_bit_cast(float, u);
}

// async global->LDS, 16B per lane; LDS dest = wave-uniform base + lane*16
__device__ __forceinline__ void gll16(const u16* g, u16* l) {
  __builtin_amdgcn_global_load_lds(
      (const __attribute__((address_space(1))) void*)g,
      (__attribute__((address_space(3))) void*)l, 16, 0, 0);
}

// ---------------- degree / CSR build ----------------

__global__ void k_count(const int* __restrict__ col, int* __restrict__ cnt) {
  int e = blockIdx.x * 256 + threadIdx.x;
  if (e < E) atomicAdd(&cnt[col[e]], 1);
}

__global__ void k_dinv(const int* __restrict__ cnt, float* __restrict__ dinv) {
  int v = blockIdx.x * 256 + threadIdx.x;
  if (v < N) dinv[v] = rsqrtf((float)cnt[v] + 1.0f);   // +1 self loop
}

__global__ void k_chunk_sum(const int* __restrict__ cnt, int* __restrict__ csum) {
  __shared__ int sp[SCAN_CH / 64];
  int i = blockIdx.x * SCAN_CH + threadIdx.x;
  int v = (i < N) ? cnt[i] : 0;
  for (int off = 32; off > 0; off >>= 1) v += __shfl_down(v, off, 64);
  if ((threadIdx.x & 63) == 0) sp[threadIdx.x >> 6] = v;
  __syncthreads();
  if (threadIdx.x == 0) {
    int s = 0;
    #pragma unroll
    for (int w = 0; w < SCAN_CH / 64; ++w) s += sp[w];
    csum[blockIdx.x] = s;
  }
}

__global__ void k_chunk_scan(const int* __restrict__ csum, int* __restrict__ coff) {
  if (blockIdx.x == 0 && threadIdx.x == 0) {
    int run = 0;
    for (int b = 0; b < NCH; ++b) { coff[b] = run; run += csum[b]; }
    coff[NCH] = run;
  }
}

__global__ void k_scan_final(const int* __restrict__ cnt, const int* __restrict__ coff,
                             int* __restrict__ offv) {
  __shared__ int s[SCAN_CH];
  int tid = threadIdx.x;
  int i = blockIdx.x * SCAN_CH + tid;
  int v = (i < N) ? cnt[i] : 0;
  s[tid] = v;
  __syncthreads();
  for (int st = 1; st < SCAN_CH; st <<= 1) {
    int tv = (tid >= st) ? s[tid - st] : 0;
    __syncthreads();
    s[tid] += tv;
    __syncthreads();
  }
  if (i < N) offv[i] = coff[blockIdx.x] + s[tid] - v;   // exclusive
  if (blockIdx.x == 0 && tid == 0) offv[N] = coff[NCH];
}

__global__ void k_fill(const int* __restrict__ row, const int* __restrict__ col,
                       const float* __restrict__ dinv, const int* __restrict__ offv,
                       int* __restrict__ cursor, int* __restrict__ csr_src,
                       float* __restrict__ csr_norm) {
  int e = blockIdx.x * 256 + threadIdx.x;
  if (e >= E) return;
  int r = row[e], c = col[e];
  int p = atomicAdd(&cursor[c], 1);
  int idx = offv[c] + p;
  csr_src[idx]  = r;
  csr_norm[idx] = dinv[r] * dinv[c];
}

// ---------------- weight split/transpose (once per call) ----------------
// LSTM: Bt[j][k] (j<512, k<256): k<128 -> W_ih[j][k], else W_hh[j][k-128]
__global__ void k_wsplit_lstm(const float* __restrict__ Wih, const float* __restrict__ Whh,
                              u16* __restrict__ bhi, u16* __restrict__ blo) {
  int idx = blockIdx.x * 256 + threadIdx.x;   // 512*256
  if (idx >= G * 256) return;
  int j = idx >> 8, k = idx & 255;
  float f = (k < H) ? Wih[j * H + k] : Whh[j * H + (k - H)];
  u16 h = f2bf(f);
  u16 l = f2bf(f - bf2f(h));
  bhi[idx] = h; blo[idx] = l;
}

// GCN: Bt[j][k] = W_gcn[k][j]  (128x128)
__global__ void k_wsplit_gcn(const float* __restrict__ Wg,
                             u16* __restrict__ bhi, u16* __restrict__ blo) {
  int idx = blockIdx.x * 256 + threadIdx.x;   // 128*128
  if (idx >= H * H) return;
  int j = idx >> 7, k = idx & 127;
  float f = Wg[k * H + j];
  u16 h = f2bf(f);
  u16 l = f2bf(f - bf2f(h));
  bhi[idx] = h; blo[idx] = l;
}

// ---------------- GCN GEMM (MFMA): xw = x_t @ W_gcn  (fp16 out) ----------------
// block 256 thr = 4 waves (2x2) -> 128 rows x 128 cols; K=128 (4 kblocks).
__global__ __launch_bounds__(256) void k_gcn_mfma(const float* __restrict__ X,
                                                  const u16* __restrict__ Bhi,
                                                  const u16* __restrict__ Blo,
                                                  _Float16* __restrict__ xw) {
  int lane = threadIdx.x & 63, wid = threadIdx.x >> 6;
  int wr = wid >> 1, wc = wid & 1;
  int rb = blockIdx.x * 128 + wr * 64;
  int cb = wc * 64;
  int lr = lane & 15;
  int lk = (lane >> 4) * 8;
  f32x4 acc[4][4];
  #pragma unroll
  for (int mi = 0; mi < 4; ++mi)
    #pragma unroll
    for (int ni = 0; ni < 4; ++ni) acc[mi][ni] = (f32x4)0.0f;

  #pragma unroll
  for (int kb = 0; kb < 4; ++kb) {
    int ko = kb * 32 + lk;
    bf16x8 bh[4], bl[4];
    #pragma unroll
    for (int ni = 0; ni < 4; ++ni) {
      size_t off = (size_t)(cb + ni * 16 + lr) * H + ko;
      bh[ni] = *reinterpret_cast<const bf16x8*>(Bhi + off);
      bl[ni] = *reinterpret_cast<const bf16x8*>(Blo + off);
    }
    #pragma unroll
    for (int mi = 0; mi < 4; ++mi) {
      int r = rb + mi * 16 + lr;
      r = r < N ? r : N - 1;                     // clamp (pad rows discarded)
      const float* ap = X + (size_t)r * H + ko;
      float4 a0 = *(const float4*)ap;
      float4 a1 = *(const float4*)(ap + 4);
      float fe[8] = {a0.x, a0.y, a0.z, a0.w, a1.x, a1.y, a1.z, a1.w};
      bf16x8 ah, al;
      #pragma unroll
      for (int e = 0; e < 8; ++e) {
        u16 hh = f2bf(fe[e]);
        ah[e] = (short)hh;
        al[e] = (short)f2bf(fe[e] - bf2f(hh));
      }
      #pragma unroll
      for (int ni = 0; ni < 4; ++ni) {
        acc[mi][ni] = __builtin_amdgcn_mfma_f32_16x16x32_bf16(ah, bh[ni], acc[mi][ni], 0, 0, 0);
        acc[mi][ni] = __builtin_amdgcn_mfma_f32_16x16x32_bf16(ah, bl[ni], acc[mi][ni], 0, 0, 0);
        acc[mi][ni] = __builtin_amdgcn_mfma_f32_16x16x32_bf16(al, bh[ni], acc[mi][ni], 0, 0, 0);
      }
    }
  }
  int orow = (lane >> 4) * 4;
  #pragma unroll
  for (int mi = 0; mi < 4; ++mi)
    #pragma unroll
    for (int ni = 0; ni < 4; ++ni)
      #pragma unroll
      for (int r = 0; r < 4; ++r) {
        int n = rb + mi * 16 + orow + r;
        if (n < N) xw[(size_t)n * H + cb + ni * 16 + lr] = (_Float16)acc[mi][ni][r];
      }
}

// ---------------- aggregation -> emb (bf16 hi/lo planes) ----------------
// Wave per vertex; two 32-lane halves process even/odd edges (f16x4/lane,
// 8B -> 256B/row coalesced), combined via shfl_xor(32). fp32 accumulate.
__global__ __launch_bounds__(256) void k_agg(const _Float16* __restrict__ xw,
                                             const int* __restrict__ offv,
                                             const int* __restrict__ csr_src,
                                             const float* __restrict__ csr_norm,
                                             const float* __restrict__ dinv,
                                             const float* __restrict__ bg,
                                             u16* __restrict__ Ahi,
                                             u16* __restrict__ Alo) {
  int wid = threadIdx.x >> 6, lane = threadIdx.x & 63;
  int v = blockIdx.x * 4 + wid;          // N % 4 == 0
  int half = lane >> 5, sl = lane & 31;
  int c0 = sl * 4;
  float ax = 0.f, ay = 0.f, az = 0.f, aw = 0.f;
  if (half == 0) {                       // self term once
    float dv = dinv[v];
    float w = dv * dv;
    f16x4 xs = *(const f16x4*)&xw[(size_t)v * H + c0];
    ax = (float)xs.x * w; ay = (float)xs.y * w;
    az = (float)xs.z * w; aw = (float)xs.w * w;
  }
  int e0 = offv[v], e1 = offv[v + 1];
  for (int e = e0 + half; e < e1; e += 2) {
    int s = csr_src[e]; float m = csr_norm[e];
    f16x4 x = *(const f16x4*)&xw[(size_t)s * H + c0];
    ax = fmaf((float)x.x, m, ax); ay = fmaf((float)x.y, m, ay);
    az = fmaf((float)x.z, m, az); aw = fmaf((float)x.w, m, aw);
  }
  ax += __shfl_xor(ax, 32, 64);
  ay += __shfl_xor(ay, 32, 64);
  az += __shfl_xor(az, 32, 64);
  aw += __shfl_xor(aw, 32, 64);
  float4 bb = *(const float4*)&bg[c0];
  float o0 = fmaxf(ax + bb.x, 0.f), o1 = fmaxf(ay + bb.y, 0.f);
  float o2 = fmaxf(az + bb.z, 0.f), o3 = fmaxf(aw + bb.w, 0.f);
  u16 h0 = f2bf(o0), h1 = f2bf(o1), h2 = f2bf(o2), h3 = f2bf(o3);
  size_t base = (size_t)v * 256 + c0;
  if (half == 0) {
    *(ushort4*)&Ahi[base] = make_ushort4(h0, h1, h2, h3);
  } else {
    u16 l0 = f2bf(o0 - bf2f(h0)), l1 = f2bf(o1 - bf2f(h1));
    u16 l2 = f2bf(o2 - bf2f(h2)), l3 = f2bf(o3 - bf2f(h3));
    *(ushort4*)&Alo[base] = make_ushort4(l0, l1, l2, l3);
  }
}

// ---------------- fused gates GEMM + LSTM cell (global_load_lds staged) ------
// 256 thr = 4 waves (wr x wc = 2x2). Block tile: 128 rows x 128 logical cols
// (jj = gate*32 + wc*16 + lr -> global j = gate*128 + ch0 + ...), so each wave
// holds (i,f,g,o) of the same (row, channel): cell update in-register.
// K: 8 kblocks of 32, double-buffered 2x32KB LDS staged by global_load_lds
// (16B/lane, LDS linear). Swizzle: tile = 64 row-pairs x 128B; granule
// g3=(row&1)*4+q stored at slot g3^(pair&7) -> ds_read_b128 is 2-way (free).
// Swizzle applied by PRE-SWIZZLING the global source address (rule #21).
template<bool FIRST>
__global__ __launch_bounds__(256) void k_gates_cell(const u16* __restrict__ Ahi,
                                                    const u16* __restrict__ Alo,
                                                    const u16* __restrict__ Bhi,
                                                    const u16* __restrict__ Blo,
                                                    const float* __restrict__ bih,
                                                    const float* __restrict__ bhh,
                                                    float* __restrict__ cbuf,
                                                    float* __restrict__ hbuf,
                                                    u16* __restrict__ oAhi,
                                                    u16* __restrict__ oAlo) {
  __shared__ u16 ls[2][16384];   // 2 x 32KB: [Ahi 8K][Alo 8K][Bhi 8K][Blo 8K]
  const int tid = threadIdx.x;
  const int lane = tid & 63, wid = tid >> 6;
  const int wr = wid >> 1, wc = wid & 1;
  const int lr = lane & 15;
  const int g  = lane >> 4;                 // k granule 0..3 (8 bf16 each)

  // bijective XCD-chunk swizzle (m204)
  int xcd = blockIdx.x & 7, loc = blockIdx.x >> 3;
  int wgid = (xcd < GRR ? xcd * (GQQ + 1) : GRR * (GQQ + 1) + (xcd - GRR) * GQQ) + loc;
  const int rb  = (wgid >> 2) * 128;
  const int ch0 = (wgid & 3) * 32;

  f32x4 acc[4][4];
  #pragma unroll
  for (int mi = 0; mi < 4; ++mi)
    #pragma unroll
    for (int ni = 0; ni < 4; ++ni) acc[mi][ni] = (f32x4)0.0f;

  // stage one 32KB k-block tile (async, no data registers)
  auto stage = [&](int buf, int kb) {
    int ko = kb * 32;
    u16* lb = &ls[buf][0];
    #pragma unroll
    for (int i = 0; i < 2; ++i) {
      int c = i * 256 + tid;               // 16B chunk id 0..511 per section
      int p = c >> 3, gs = c & 7;
      int g3 = gs ^ (p & 7);               // pre-swizzled global granule
      int row = p * 2 + (g3 >> 2);
      int q = g3 & 3;
      size_t ga = (size_t)(rb + row) * 256 + ko + q * 8;
      gll16(Ahi + ga, lb + c * 8);
      gll16(Alo + ga, lb + 4096 + c * 8);
      int j = (row >> 5) * 128 + ch0 + (row & 31);
      size_t gb = (size_t)j * 256 + ko + q * 8;
      gll16(Bhi + gb, lb + 8192 + c * 8);
      gll16(Blo + gb, lb + 12288 + c * 8);
    }
  };

  auto compute = [&](int buf) {
    const u16* lb = &ls[buf][0];
    bf16x8 bh[4], bl[4];
    #pragma unroll
    for (int ni = 0; ni < 4; ++ni) {
      int jj = ni * 32 + wc * 16 + lr;
      int p = jj >> 1;
      int g3 = ((jj & 1) << 2) | g;
      int off = p * 64 + (g3 ^ (p & 7)) * 8;
      bh[ni] = *(const bf16x8*)(lb + 8192 + off);
      bl[ni] = *(const bf16x8*)(lb + 12288 + off);
    }
    #pragma unroll
    for (int mi = 0; mi < 4; ++mi) {
      int rr = wr * 64 + mi * 16 + lr;
      int p = rr >> 1;
      int g3 = ((rr & 1) << 2) | g;
      int off = p * 64 + (g3 ^ (p & 7)) * 8;
      bf16x8 ah = *(const bf16x8*)(lb + off);
      bf16x8 al = *(const bf16x8*)(lb + 4096 + off);
      #pragma unroll
      for (int ni = 0; ni < 4; ++ni) {
        acc[mi][ni] = __builtin_amdgcn_mfma_f32_16x16x32_bf16(ah, bh[ni], acc[mi][ni], 0, 0, 0);
        acc[mi][ni] = __builtin_amdgcn_mfma_f32_16x16x32_bf16(ah, bl[ni], acc[mi][ni], 0, 0, 0);
        acc[mi][ni] = __builtin_amdgcn_mfma_f32_16x16x32_bf16(al, bh[ni], acc[mi][ni], 0, 0, 0);
      }
    }
  };

  const int kbs = FIRST ? 4 : 8;            // t=0: h==0, skip upper K half
  stage(0, 0);
  for (int kb = 0; kb < kbs; ++kb) {
    __syncthreads();                        // buf[kb&1] staged; prev reads done
    if (kb + 1 < kbs) stage((kb + 1) & 1, kb + 1);  // async, hides under MFMAs
    compute(kb & 1);
  }

  int ch = ch0 + wc * 16 + lr;
  float bi_ = bih[ch]       + bhh[ch];
  float bf_ = bih[128 + ch] + bhh[128 + ch];
  float bg_ = bih[256 + ch] + bhh[256 + ch];
  float bo_ = bih[384 + ch] + bhh[384 + ch];
  int orow = (lane >> 4) * 4;
  int rbw = rb + wr * 64;
  #pragma unroll
  for (int mi = 0; mi < 4; ++mi) {
    #pragma unroll
    for (int r = 0; r < 4; ++r) {
      int n = rbw + mi * 16 + orow + r;
      if (n >= N) continue;
      float gi = acc[mi][0][r] + bi_;
      float gf = acc[mi][1][r] + bf_;
      float gg = acc[mi][2][r] + bg_;
      float go = acc[mi][3][r] + bo_;
      float si = 1.f / (1.f + expf(-gi));
      float sf = 1.f / (1.f + expf(-gf));
      float so = 1.f / (1.f + expf(-go));
      float tg = tanhf(gg);
      size_t ci = (size_t)n * H + ch;
      float cn = FIRST ? si * tg : fmaf(sf, cbuf[ci], si * tg);
      cbuf[ci] = cn;
      float hn = so * tanhf(cn);
      hbuf[ci] = hn;
      u16 hv = f2bf(hn);
      size_t ab = (size_t)n * 256 + 128 + ch;
      oAhi[ab] = hv;
      oAlo[ab] = f2bf(hn - bf2f(hv));
    }
  }
}

// ---------------- FC per step: out[n][t][:] = h[n] @ W_fc^T + b_fc ----------------
__global__ __launch_bounds__(256, 3) void k_fc(const float* __restrict__ h,
                                               const float* __restrict__ Wfc,
                                               const float* __restrict__ bfc,
                                               float* __restrict__ outp, int t) {
  __shared__ float hsT[128][68];
  __shared__ float wT[128][36];
  int tid = threadIdx.x;
  int n0 = blockIdx.x * 64;
  for (int i = 0; i < 32; ++i) {
    int idx = i * 256 + tid;
    int r = idx >> 7, k = idx & 127;
    hsT[k][r] = (n0 + r < N) ? h[(size_t)(n0 + r) * H + k] : 0.0f;
  }
  for (int i = 0; i < 16; ++i) {
    int idx = i * 256 + tid;          // 4096 = 32*128
    int oc = idx >> 7, k = idx & 127;
    wT[k][oc] = Wfc[idx];
  }
  __syncthreads();
  int og = tid & 15, rg = tid >> 4;   // 16 oc-groups x 16 row-groups
  int oc0 = og * 2, r0 = rg * 4;
  float acc[4][2] = {};
  #pragma unroll 2
  for (int k = 0; k < 128; ++k) {
    float4 a = *(const float4*)&hsT[k][r0];
    float2 w = *(const float2*)&wT[k][oc0];
    float ar[4] = {a.x, a.y, a.z, a.w};
    #pragma unroll
    for (int i = 0; i < 4; ++i) {
      acc[i][0] = fmaf(ar[i], w.x, acc[i][0]);
      acc[i][1] = fmaf(ar[i], w.y, acc[i][1]);
    }
  }
  float b0 = bfc[oc0], b1 = bfc[oc0 + 1];
  #pragma unroll
  for (int i = 0; i < 4; ++i) {
    int n = n0 + r0 + i;
    if (n < N) {
      size_t ob = ((size_t)n * T + t) * OUTD + oc0;
      outp[ob]     = acc[i][0] + b0;
      outp[ob + 1] = acc[i][1] + b1;
    }
  }
}

// ---------------------------------------------------------------------------

extern "C" void kernel_launch(void* const* d_in, const int* in_sizes, int n_in,
                              void* d_out, int out_size, void* d_ws, size_t ws_size,
                              hipStream_t stream) {
  const float* x_seq = (const float*)d_in[0];
  const int*   eidx  = (const int*)d_in[1];
  const int*   erow  = eidx;          // sources
  const int*   ecol  = eidx + E;      // targets
  const float* W_gcn = (const float*)d_in[2];
  const float* b_gcn = (const float*)d_in[3];
  const float* W_ih  = (const float*)d_in[4];
  const float* W_hh  = (const float*)d_in[5];
  const float* b_ih  = (const float*)d_in[6];
  const float* b_hh  = (const float*)d_in[7];
  const float* W_fc  = (const float*)d_in[8];
  const float* b_fc  = (const float*)d_in[9];
  float* outp = (float*)d_out;

  char* base = (char*)d_ws;
  size_t o = 0;
  auto alloc = [&](size_t bytes) -> void* {
    void* p = base + o;
    o += (bytes + 255) & ~(size_t)255;
    return p;
  };
  int*   cnt      = (int*)  alloc((size_t)N * 4);
  int*   cursor   = (int*)  alloc((size_t)N * 4);
  int*   offv     = (int*)  alloc((size_t)(N + 1) * 4);
  int*   csum     = (int*)  alloc((size_t)(NCH + 1) * 4);
  int*   coff     = (int*)  alloc((size_t)(NCH + 1) * 4);
  float* dinv     = (float*)alloc((size_t)N * 4);
  int*   csr_src  = (int*)  alloc((size_t)E * 4);
  float* csr_norm = (float*)alloc((size_t)E * 4);
  u16*   bt_hi    = (u16*)  alloc((size_t)G * 256 * 2);
  u16*   bt_lo    = (u16*)  alloc((size_t)G * 256 * 2);
  u16*   bg_hi    = (u16*)  alloc((size_t)H * H * 2);
  u16*   bg_lo    = (u16*)  alloc((size_t)H * H * 2);
  u16*   a_hi0    = (u16*)  alloc((size_t)NP * 256 * 2);   // [emb | h] bf16-hi, even t
  u16*   a_lo0    = (u16*)  alloc((size_t)NP * 256 * 2);
  u16*   a_hi1    = (u16*)  alloc((size_t)NP * 256 * 2);   // odd t
  u16*   a_lo1    = (u16*)  alloc((size_t)NP * 256 * 2);
  _Float16* xw    = (_Float16*)alloc((size_t)N * H * 2);
  float* hbuf     = (float*)alloc((size_t)N * H * 4);
  float* cbuf     = (float*)alloc((size_t)N * H * 4);
  (void)ws_size; (void)in_sizes; (void)n_in; (void)out_size;

  u16* AHI[2] = {a_hi0, a_hi1};
  u16* ALO[2] = {a_lo0, a_lo1};

  // only the small CSR counters need zeroing; h/c state handled by the
  // FIRST-step specialization; pad rows only affect discarded output rows.
  hipMemsetAsync(cnt,    0, (size_t)N * 4, stream);
  hipMemsetAsync(cursor, 0, (size_t)N * 4, stream);

  k_count<<<E / 256, 256, 0, stream>>>(ecol, cnt);
  k_dinv<<<(N + 255) / 256, 256, 0, stream>>>(cnt, dinv);
  k_chunk_sum<<<NCH, SCAN_CH, 0, stream>>>(cnt, csum);
  k_chunk_scan<<<1, 64, 0, stream>>>(csum, coff);
  k_scan_final<<<NCH, SCAN_CH, 0, stream>>>(cnt, coff, offv);
  k_fill<<<E / 256, 256, 0, stream>>>(erow, ecol, dinv, offv, cursor, csr_src, csr_norm);
  k_wsplit_lstm<<<(G * 256) / 256, 256, 0, stream>>>(W_ih, W_hh, bt_hi, bt_lo);
  k_wsplit_gcn<<<(H * H) / 256, 256, 0, stream>>>(W_gcn, bg_hi, bg_lo);

  int gblocks = NP / 128;                 // 391, for k_gcn_mfma
  int rblocks = (N + 63) / 64;            // for k_fc
  for (int t = 0; t < T; ++t) {
    int cur = t & 1, nxt = cur ^ 1;
    const float* xt = x_seq + (size_t)t * N * H;
    k_gcn_mfma<<<gblocks, 256, 0, stream>>>(xt, bg_hi, bg_lo, xw);
    k_agg<<<N / 4, 256, 0, stream>>>(xw, offv, csr_src, csr_norm, dinv, b_gcn,
                                     AHI[cur], ALO[cur]);
    if (t == 0)
      k_gates_cell<true><<<GNWG, 256, 0, stream>>>(
          AHI[cur], ALO[cur], bt_hi, bt_lo, b_ih, b_hh, cbuf, hbuf, AHI[nxt], ALO[nxt]);
    else
      k_gates_cell<false><<<GNWG, 256, 0, stream>>>(
          AHI[cur], ALO[cur], bt_hi, bt_lo, b_ih, b_hh, cbuf, hbuf, AHI[nxt], ALO[nxt]);
    k_fc<<<rblocks, 256, 0, stream>>>(hbuf, W_fc, b_fc, outp, t);
  }
}

// Round 9
// 1844.673 us; speedup vs baseline: 1.7350x; 1.1554x over previous
//
#include <hip/hip_runtime.h>
#include <cstdint>
#include <cstddef>

// ---------------------------------------------------------------------------
// GCN(1 layer, sym-norm w/ self loops) -> LSTM(1 layer, T=9) -> FC, eval mode
// Round 9: gates GEMM in single fp16 (A planes + LSTM weights fp16, 1 MFMA
// per fragment pair, staging halved; error budget analyzed ~3e-4 < 7.4e-4);
// CSR entries packed int2 (one 8B scatter per edge, halves k_fill write amp).
// GCN GEMM keeps bf16 hi/lo split (fp32-grade) to isolate the precision change.
// ---------------------------------------------------------------------------

constexpr int N    = 50000;
constexpr int NP   = 50048;  // padded to 128-row strips (391*128)
constexpr int E    = 1600000;
constexpr int T    = 9;
constexpr int H    = 128;    // F_IN == H == 128
constexpr int G    = 512;    // 4*H (gates i,f,g,o)
constexpr int OUTD = 32;

constexpr int SCAN_CH = 512;
constexpr int NCH = (N + SCAN_CH - 1) / SCAN_CH;   // 98

// gates grid: 391 row-strips x 4 col-quarters
constexpr int GNWG = (NP / 128) * 4;               // 1564
constexpr int GQQ  = GNWG / 8;                     // 195
constexpr int GRR  = GNWG % 8;                     // 4

typedef __attribute__((ext_vector_type(8))) short bf16x8;
typedef __attribute__((ext_vector_type(8))) _Float16 f16x8;
typedef __attribute__((ext_vector_type(4))) float f32x4;
typedef __attribute__((ext_vector_type(4))) _Float16 f16x4;
typedef unsigned short u16;

__device__ __forceinline__ u16 f2bf(float f) {        // RNE f32 -> bf16 bits
  unsigned u = __builtin_bit_cast(unsigned, f);
  u += 0x7fffu + ((u >> 16) & 1u);
  return (u16)(u >> 16);
}
__device__ __forceinline__ float bf2f(u16 h) {
  unsigned u = ((unsigned)h) << 16;
  return __builtin_bit_cast(float, u);
}

// async global->LDS, 16B per lane; LDS dest = wave-uniform base + lane*16
__device__ __forceinline__ void gll16(const void* g, void* l) {
  __builtin_amdgcn_global_load_lds(
      (const __attribute__((address_space(1))) void*)g,
      (__attribute__((address_space(3))) void*)l, 16, 0, 0);
}

// ---------------- degree / CSR build ----------------

__global__ void k_count(const int* __restrict__ col, int* __restrict__ cnt) {
  int e = blockIdx.x * 256 + threadIdx.x;
  if (e < E) atomicAdd(&cnt[col[e]], 1);
}

__global__ void k_dinv(const int* __restrict__ cnt, float* __restrict__ dinv) {
  int v = blockIdx.x * 256 + threadIdx.x;
  if (v < N) dinv[v] = rsqrtf((float)cnt[v] + 1.0f);   // +1 self loop
}

__global__ void k_chunk_sum(const int* __restrict__ cnt, int* __restrict__ csum) {
  __shared__ int sp[SCAN_CH / 64];
  int i = blockIdx.x * SCAN_CH + threadIdx.x;
  int v = (i < N) ? cnt[i] : 0;
  for (int off = 32; off > 0; off >>= 1) v += __shfl_down(v, off, 64);
  if ((threadIdx.x & 63) == 0) sp[threadIdx.x >> 6] = v;
  __syncthreads();
  if (threadIdx.x == 0) {
    int s = 0;
    #pragma unroll
    for (int w = 0; w < SCAN_CH / 64; ++w) s += sp[w];
    csum[blockIdx.x] = s;
  }
}

__global__ void k_chunk_scan(const int* __restrict__ csum, int* __restrict__ coff) {
  if (blockIdx.x == 0 && threadIdx.x == 0) {
    int run = 0;
    for (int b = 0; b < NCH; ++b) { coff[b] = run; run += csum[b]; }
    coff[NCH] = run;
  }
}

__global__ void k_scan_final(const int* __restrict__ cnt, const int* __restrict__ coff,
                             int* __restrict__ offv) {
  __shared__ int s[SCAN_CH];
  int tid = threadIdx.x;
  int i = blockIdx.x * SCAN_CH + tid;
  int v = (i < N) ? cnt[i] : 0;
  s[tid] = v;
  __syncthreads();
  for (int st = 1; st < SCAN_CH; st <<= 1) {
    int tv = (tid >= st) ? s[tid - st] : 0;
    __syncthreads();
    s[tid] += tv;
    __syncthreads();
  }
  if (i < N) offv[i] = coff[blockIdx.x] + s[tid] - v;   // exclusive
  if (blockIdx.x == 0 && tid == 0) offv[N] = coff[NCH];
}

// packed CSR entry: one 8B scatter per edge (halves write amplification)
__global__ void k_fill(const int* __restrict__ row, const int* __restrict__ col,
                       const float* __restrict__ dinv, const int* __restrict__ offv,
                       int* __restrict__ cursor, int2* __restrict__ csr) {
  int e = blockIdx.x * 256 + threadIdx.x;
  if (e >= E) return;
  int r = row[e], c = col[e];
  int p = atomicAdd(&cursor[c], 1);
  float nm = dinv[r] * dinv[c];
  csr[offv[c] + p] = make_int2(r, __builtin_bit_cast(int, nm));
}

// ---------------- weight prep (once per call) ----------------
// LSTM: bt[j][k] fp16 (j<512, k<256): k<128 -> W_ih[j][k], else W_hh[j][k-128]
__global__ void k_wprep_lstm(const float* __restrict__ Wih, const float* __restrict__ Whh,
                             _Float16* __restrict__ bt) {
  int idx = blockIdx.x * 256 + threadIdx.x;   // 512*256
  if (idx >= G * 256) return;
  int j = idx >> 8, k = idx & 255;
  float f = (k < H) ? Wih[j * H + k] : Whh[j * H + (k - H)];
  bt[idx] = (_Float16)f;
}

// GCN: Bt[j][k] = W_gcn[k][j]  (128x128), bf16 hi/lo (accurate path)
__global__ void k_wsplit_gcn(const float* __restrict__ Wg,
                             u16* __restrict__ bhi, u16* __restrict__ blo) {
  int idx = blockIdx.x * 256 + threadIdx.x;   // 128*128
  if (idx >= H * H) return;
  int j = idx >> 7, k = idx & 127;
  float f = Wg[k * H + j];
  u16 h = f2bf(f);
  u16 l = f2bf(f - bf2f(h));
  bhi[idx] = h; blo[idx] = l;
}

// ---------------- GCN GEMM (MFMA): xw = x_t @ W_gcn  (fp16 out) ----------------
// block 256 thr = 4 waves (2x2) -> 128 rows x 128 cols; K=128 (4 kblocks).
__global__ __launch_bounds__(256) void k_gcn_mfma(const float* __restrict__ X,
                                                  const u16* __restrict__ Bhi,
                                                  const u16* __restrict__ Blo,
                                                  _Float16* __restrict__ xw) {
  int lane = threadIdx.x & 63, wid = threadIdx.x >> 6;
  int wr = wid >> 1, wc = wid & 1;
  int rb = blockIdx.x * 128 + wr * 64;
  int cb = wc * 64;
  int lr = lane & 15;
  int lk = (lane >> 4) * 8;
  f32x4 acc[4][4];
  #pragma unroll
  for (int mi = 0; mi < 4; ++mi)
    #pragma unroll
    for (int ni = 0; ni < 4; ++ni) acc[mi][ni] = (f32x4)0.0f;

  #pragma unroll
  for (int kb = 0; kb < 4; ++kb) {
    int ko = kb * 32 + lk;
    bf16x8 bh[4], bl[4];
    #pragma unroll
    for (int ni = 0; ni < 4; ++ni) {
      size_t off = (size_t)(cb + ni * 16 + lr) * H + ko;
      bh[ni] = *reinterpret_cast<const bf16x8*>(Bhi + off);
      bl[ni] = *reinterpret_cast<const bf16x8*>(Blo + off);
    }
    #pragma unroll
    for (int mi = 0; mi < 4; ++mi) {
      int r = rb + mi * 16 + lr;
      r = r < N ? r : N - 1;                     // clamp (pad rows discarded)
      const float* ap = X + (size_t)r * H + ko;
      float4 a0 = *(const float4*)ap;
      float4 a1 = *(const float4*)(ap + 4);
      float fe[8] = {a0.x, a0.y, a0.z, a0.w, a1.x, a1.y, a1.z, a1.w};
      bf16x8 ah, al;
      #pragma unroll
      for (int e = 0; e < 8; ++e) {
        u16 hh = f2bf(fe[e]);
        ah[e] = (short)hh;
        al[e] = (short)f2bf(fe[e] - bf2f(hh));
      }
      #pragma unroll
      for (int ni = 0; ni < 4; ++ni) {
        acc[mi][ni] = __builtin_amdgcn_mfma_f32_16x16x32_bf16(ah, bh[ni], acc[mi][ni], 0, 0, 0);
        acc[mi][ni] = __builtin_amdgcn_mfma_f32_16x16x32_bf16(ah, bl[ni], acc[mi][ni], 0, 0, 0);
        acc[mi][ni] = __builtin_amdgcn_mfma_f32_16x16x32_bf16(al, bh[ni], acc[mi][ni], 0, 0, 0);
      }
    }
  }
  int orow = (lane >> 4) * 4;
  #pragma unroll
  for (int mi = 0; mi < 4; ++mi)
    #pragma unroll
    for (int ni = 0; ni < 4; ++ni)
      #pragma unroll
      for (int r = 0; r < 4; ++r) {
        int n = rb + mi * 16 + orow + r;
        if (n < N) xw[(size_t)n * H + cb + ni * 16 + lr] = (_Float16)acc[mi][ni][r];
      }
}

// ---------------- aggregation -> emb (fp16 A plane, cols 0..127) ----------------
// Wave per vertex; two 32-lane halves process even/odd edges (f16x4/lane,
// 8B -> 256B/row coalesced), combined via shfl_xor(32). fp32 accumulate.
__global__ __launch_bounds__(256) void k_agg(const _Float16* __restrict__ xw,
                                             const int* __restrict__ offv,
                                             const int2* __restrict__ csr,
                                             const float* __restrict__ dinv,
                                             const float* __restrict__ bg,
                                             _Float16* __restrict__ A) {
  int wid = threadIdx.x >> 6, lane = threadIdx.x & 63;
  int v = blockIdx.x * 4 + wid;          // N % 4 == 0
  int half = lane >> 5, sl = lane & 31;
  int c0 = sl * 4;
  float ax = 0.f, ay = 0.f, az = 0.f, aw = 0.f;
  if (half == 0) {                       // self term once
    float dv = dinv[v];
    float w = dv * dv;
    f16x4 xs = *(const f16x4*)&xw[(size_t)v * H + c0];
    ax = (float)xs.x * w; ay = (float)xs.y * w;
    az = (float)xs.z * w; aw = (float)xs.w * w;
  }
  int e0 = offv[v], e1 = offv[v + 1];
  for (int e = e0 + half; e < e1; e += 2) {
    int2 en = csr[e];
    int s = en.x; float m = __builtin_bit_cast(float, en.y);
    f16x4 x = *(const f16x4*)&xw[(size_t)s * H + c0];
    ax = fmaf((float)x.x, m, ax); ay = fmaf((float)x.y, m, ay);
    az = fmaf((float)x.z, m, az); aw = fmaf((float)x.w, m, aw);
  }
  ax += __shfl_xor(ax, 32, 64);
  ay += __shfl_xor(ay, 32, 64);
  az += __shfl_xor(az, 32, 64);
  aw += __shfl_xor(aw, 32, 64);
  if (half == 0) {
    float4 bb = *(const float4*)&bg[c0];
    f16x4 ov;
    ov.x = (_Float16)fmaxf(ax + bb.x, 0.f);
    ov.y = (_Float16)fmaxf(ay + bb.y, 0.f);
    ov.z = (_Float16)fmaxf(az + bb.z, 0.f);
    ov.w = (_Float16)fmaxf(aw + bb.w, 0.f);
    *(f16x4*)&A[(size_t)v * 256 + c0] = ov;
  }
}

// ---------------- fused gates GEMM + LSTM cell (fp16, global_load_lds) ------
// 256 thr = 4 waves (wr x wc = 2x2). Block tile: 128 rows x 128 logical cols
// (jj = gate*32 + wc*16 + lr -> global j = gate*128 + ch0 + ...), so each wave
// holds (i,f,g,o) of the same (row, channel): cell update in-register.
// K: 8 kblocks of 32 fp16; double-buffered 2x16KB LDS via global_load_lds.
// Row = 64B (4x16B granules); swizzle slot = q ^ ((row>>1)&3) -> 2-way reads
// (free); applied by pre-swizzling the GLOBAL source granule (rule #21).
template<bool FIRST>
__global__ __launch_bounds__(256) void k_gates_cell(const _Float16* __restrict__ A,
                                                    const _Float16* __restrict__ Bt,
                                                    const float* __restrict__ bih,
                                                    const float* __restrict__ bhh,
                                                    float* __restrict__ cbuf,
                                                    float* __restrict__ hbuf,
                                                    _Float16* __restrict__ oA) {
  __shared__ _Float16 ls[2][8192];   // 2 x 16KB: [A 8KB | B 8KB]
  const int tid = threadIdx.x;
  const int lane = tid & 63, wid = tid >> 6;
  const int wr = wid >> 1, wc = wid & 1;
  const int lr = lane & 15;
  const int g  = lane >> 4;                 // k granule 0..3 (8 fp16 each)

  // bijective XCD-chunk swizzle (m204)
  int xcd = blockIdx.x & 7, loc = blockIdx.x >> 3;
  int wgid = (xcd < GRR ? xcd * (GQQ + 1) : GRR * (GQQ + 1) + (xcd - GRR) * GQQ) + loc;
  const int rb  = (wgid >> 2) * 128;
  const int ch0 = (wgid & 3) * 32;

  f32x4 acc[4][4];
  #pragma unroll
  for (int mi = 0; mi < 4; ++mi)
    #pragma unroll
    for (int ni = 0; ni < 4; ++ni) acc[mi][ni] = (f32x4)0.0f;

  // stage one 16KB k-block tile (async, no data registers)
  auto stage = [&](int buf, int kb) {
    int ko = kb * 32;
    _Float16* lb = &ls[buf][0];
    #pragma unroll
    for (int i = 0; i < 2; ++i) {
      int c = i * 256 + tid;               // 16B chunk id 0..511
      int row = c >> 2, slot = c & 3;
      int g3 = slot ^ ((row >> 1) & 3);    // pre-swizzled global granule
      size_t ga = (size_t)(rb + row) * 256 + ko + g3 * 8;
      gll16(A + ga, lb + c * 8);
      int j = (row >> 5) * 128 + ch0 + (row & 31);
      size_t gb = (size_t)j * 256 + ko + g3 * 8;
      gll16(Bt + gb, lb + 4096 + c * 8);
    }
  };

  auto compute = [&](int buf) {
    const _Float16* lb = &ls[buf][0];
    f16x8 bfr[4];
    #pragma unroll
    for (int ni = 0; ni < 4; ++ni) {
      int jj = ni * 32 + wc * 16 + lr;
      bfr[ni] = *(const f16x8*)(lb + 4096 + jj * 32 + (g ^ ((jj >> 1) & 3)) * 8);
    }
    #pragma unroll
    for (int mi = 0; mi < 4; ++mi) {
      int rr = wr * 64 + mi * 16 + lr;
      f16x8 afr = *(const f16x8*)(lb + rr * 32 + (g ^ ((rr >> 1) & 3)) * 8);
      #pragma unroll
      for (int ni = 0; ni < 4; ++ni)
        acc[mi][ni] = __builtin_amdgcn_mfma_f32_16x16x32_f16(afr, bfr[ni], acc[mi][ni], 0, 0, 0);
    }
  };

  const int kbs = FIRST ? 4 : 8;            // t=0: h==0, skip upper K half
  stage(0, 0);
  for (int kb = 0; kb < kbs; ++kb) {
    __syncthreads();                        // buf[kb&1] staged; prev reads done
    if (kb + 1 < kbs) stage((kb + 1) & 1, kb + 1);  // async, hides under MFMAs
    compute(kb & 1);
  }

  int ch = ch0 + wc * 16 + lr;
  float bi_ = bih[ch]       + bhh[ch];
  float bf_ = bih[128 + ch] + bhh[128 + ch];
  float bg_ = bih[256 + ch] + bhh[256 + ch];
  float bo_ = bih[384 + ch] + bhh[384 + ch];
  int orow = (lane >> 4) * 4;
  int rbw = rb + wr * 64;
  #pragma unroll
  for (int mi = 0; mi < 4; ++mi) {
    #pragma unroll
    for (int r = 0; r < 4; ++r) {
      int n = rbw + mi * 16 + orow + r;
      if (n >= N) continue;
      float gi = acc[mi][0][r] + bi_;
      float gf = acc[mi][1][r] + bf_;
      float gg = acc[mi][2][r] + bg_;
      float go = acc[mi][3][r] + bo_;
      float si = 1.f / (1.f + expf(-gi));
      float sf = 1.f / (1.f + expf(-gf));
      float so = 1.f / (1.f + expf(-go));
      float tg = tanhf(gg);
      size_t ci = (size_t)n * H + ch;
      float cn = FIRST ? si * tg : fmaf(sf, cbuf[ci], si * tg);
      cbuf[ci] = cn;
      float hn = so * tanhf(cn);
      hbuf[ci] = hn;
      oA[(size_t)n * 256 + 128 + ch] = (_Float16)hn;
    }
  }
}

// ---------------- FC per step: out[n][t][:] = h[n] @ W_fc^T + b_fc ----------------
__global__ __launch_bounds__(256, 3) void k_fc(const float* __restrict__ h,
                                               const float* __restrict__ Wfc,
                                               const float* __restrict__ bfc,
                                               float* __restrict__ outp, int t) {
  __shared__ float hsT[128][68];
  __shared__ float wT[128][36];
  int tid = threadIdx.x;
  int n0 = blockIdx.x * 64;
  for (int i = 0; i < 32; ++i) {
    int idx = i * 256 + tid;
    int r = idx >> 7, k = idx & 127;
    hsT[k][r] = (n0 + r < N) ? h[(size_t)(n0 + r) * H + k] : 0.0f;
  }
  for (int i = 0; i < 16; ++i) {
    int idx = i * 256 + tid;          // 4096 = 32*128
    int oc = idx >> 7, k = idx & 127;
    wT[k][oc] = Wfc[idx];
  }
  __syncthreads();
  int og = tid & 15, rg = tid >> 4;   // 16 oc-groups x 16 row-groups
  int oc0 = og * 2, r0 = rg * 4;
  float acc[4][2] = {};
  #pragma unroll 2
  for (int k = 0; k < 128; ++k) {
    float4 a = *(const float4*)&hsT[k][r0];
    float2 w = *(const float2*)&wT[k][oc0];
    float ar[4] = {a.x, a.y, a.z, a.w};
    #pragma unroll
    for (int i = 0; i < 4; ++i) {
      acc[i][0] = fmaf(ar[i], w.x, acc[i][0]);
      acc[i][1] = fmaf(ar[i], w.y, acc[i][1]);
    }
  }
  float b0 = bfc[oc0], b1 = bfc[oc0 + 1];
  #pragma unroll
  for (int i = 0; i < 4; ++i) {
    int n = n0 + r0 + i;
    if (n < N) {
      size_t ob = ((size_t)n * T + t) * OUTD + oc0;
      outp[ob]     = acc[i][0] + b0;
      outp[ob + 1] = acc[i][1] + b1;
    }
  }
}

// ---------------------------------------------------------------------------

extern "C" void kernel_launch(void* const* d_in, const int* in_sizes, int n_in,
                              void* d_out, int out_size, void* d_ws, size_t ws_size,
                              hipStream_t stream) {
  const float* x_seq = (const float*)d_in[0];
  const int*   eidx  = (const int*)d_in[1];
  const int*   erow  = eidx;          // sources
  const int*   ecol  = eidx + E;      // targets
  const float* W_gcn = (const float*)d_in[2];
  const float* b_gcn = (const float*)d_in[3];
  const float* W_ih  = (const float*)d_in[4];
  const float* W_hh  = (const float*)d_in[5];
  const float* b_ih  = (const float*)d_in[6];
  const float* b_hh  = (const float*)d_in[7];
  const float* W_fc  = (const float*)d_in[8];
  const float* b_fc  = (const float*)d_in[9];
  float* outp = (float*)d_out;

  char* base = (char*)d_ws;
  size_t o = 0;
  auto alloc = [&](size_t bytes) -> void* {
    void* p = base + o;
    o += (bytes + 255) & ~(size_t)255;
    return p;
  };
  int*   cnt      = (int*)  alloc((size_t)N * 4);
  int*   cursor   = (int*)  alloc((size_t)N * 4);
  int*   offv     = (int*)  alloc((size_t)(N + 1) * 4);
  int*   csum     = (int*)  alloc((size_t)(NCH + 1) * 4);
  int*   coff     = (int*)  alloc((size_t)(NCH + 1) * 4);
  float* dinv     = (float*)alloc((size_t)N * 4);
  int2*  csr      = (int2*) alloc((size_t)E * 8);
  _Float16* bt    = (_Float16*)alloc((size_t)G * 256 * 2);
  u16*   bg_hi    = (u16*)  alloc((size_t)H * H * 2);
  u16*   bg_lo    = (u16*)  alloc((size_t)H * H * 2);
  _Float16* a0    = (_Float16*)alloc((size_t)NP * 256 * 2);  // [emb | h] fp16, even t
  _Float16* a1    = (_Float16*)alloc((size_t)NP * 256 * 2);  // odd t
  _Float16* xw    = (_Float16*)alloc((size_t)N * H * 2);
  float* hbuf     = (float*)alloc((size_t)N * H * 4);
  float* cbuf     = (float*)alloc((size_t)N * H * 4);
  (void)ws_size; (void)in_sizes; (void)n_in; (void)out_size;

  _Float16* AP[2] = {a0, a1};

  // only the small CSR counters need zeroing; h/c state handled by the
  // FIRST-step specialization; pad rows only affect discarded output rows.
  hipMemsetAsync(cnt,    0, (size_t)N * 4, stream);
  hipMemsetAsync(cursor, 0, (size_t)N * 4, stream);

  k_count<<<E / 256, 256, 0, stream>>>(ecol, cnt);
  k_dinv<<<(N + 255) / 256, 256, 0, stream>>>(cnt, dinv);
  k_chunk_sum<<<NCH, SCAN_CH, 0, stream>>>(cnt, csum);
  k_chunk_scan<<<1, 64, 0, stream>>>(csum, coff);
  k_scan_final<<<NCH, SCAN_CH, 0, stream>>>(cnt, coff, offv);
  k_fill<<<E / 256, 256, 0, stream>>>(erow, ecol, dinv, offv, cursor, csr);
  k_wprep_lstm<<<(G * 256) / 256, 256, 0, stream>>>(W_ih, W_hh, bt);
  k_wsplit_gcn<<<(H * H) / 256, 256, 0, stream>>>(W_gcn, bg_hi, bg_lo);

  int gblocks = NP / 128;                 // 391, for k_gcn_mfma
  int rblocks = (N + 63) / 64;            // for k_fc
  for (int t = 0; t < T; ++t) {
    int cur = t & 1, nxt = cur ^ 1;
    const float* xt = x_seq + (size_t)t * N * H;
    k_gcn_mfma<<<gblocks, 256, 0, stream>>>(xt, bg_hi, bg_lo, xw);
    k_agg<<<N / 4, 256, 0, stream>>>(xw, offv, csr, dinv, b_gcn, AP[cur]);
    if (t == 0)
      k_gates_cell<true><<<GNWG, 256, 0, stream>>>(
          AP[cur], bt, b_ih, b_hh, cbuf, hbuf, AP[nxt]);
    else
      k_gates_cell<false><<<GNWG, 256, 0, stream>>>(
          AP[cur], bt, b_ih, b_hh, cbuf, hbuf, AP[nxt]);
    k_fc<<<rblocks, 256, 0, stream>>>(hbuf, W_fc, b_fc, outp, t);
  }
}

// Round 10
// 1771.197 us; speedup vs baseline: 1.8070x; 1.0415x over previous
//
#include <hip/hip_runtime.h>
#include <cstdint>
#include <cstddef>

// ---------------------------------------------------------------------------
// GCN(1 layer, sym-norm w/ self loops) -> LSTM(1 layer, T=9) -> FC, eval mode
// Round 10: GCN GEMM -> single fp16 (W in swizzled LDS, 64 MFMAs/wave, 1 cvt
// per A elem); h unified to fp16 A-plane (gates drops hbuf write, fc reads
// fp16 h). Gates/agg/CSR unchanged from round 9.
// ---------------------------------------------------------------------------

constexpr int N    = 50000;
constexpr int NP   = 50048;  // padded to 128-row strips (391*128)
constexpr int E    = 1600000;
constexpr int T    = 9;
constexpr int H    = 128;    // F_IN == H == 128
constexpr int G    = 512;    // 4*H (gates i,f,g,o)
constexpr int OUTD = 32;

constexpr int SCAN_CH = 512;
constexpr int NCH = (N + SCAN_CH - 1) / SCAN_CH;   // 98

// gates grid: 391 row-strips x 4 col-quarters
constexpr int GNWG = (NP / 128) * 4;               // 1564
constexpr int GQQ  = GNWG / 8;                     // 195
constexpr int GRR  = GNWG % 8;                     // 4

typedef __attribute__((ext_vector_type(8))) short bf16x8;
typedef __attribute__((ext_vector_type(8))) _Float16 f16x8;
typedef __attribute__((ext_vector_type(4))) float f32x4;
typedef __attribute__((ext_vector_type(4))) _Float16 f16x4;
typedef unsigned short u16;

// async global->LDS, 16B per lane; LDS dest = wave-uniform base + lane*16
__device__ __forceinline__ void gll16(const void* g, void* l) {
  __builtin_amdgcn_global_load_lds(
      (const __attribute__((address_space(1))) void*)g,
      (__attribute__((address_space(3))) void*)l, 16, 0, 0);
}

// ---------------- degree / CSR build ----------------

__global__ void k_count(const int* __restrict__ col, int* __restrict__ cnt) {
  int e = blockIdx.x * 256 + threadIdx.x;
  if (e < E) atomicAdd(&cnt[col[e]], 1);
}

__global__ void k_dinv(const int* __restrict__ cnt, float* __restrict__ dinv) {
  int v = blockIdx.x * 256 + threadIdx.x;
  if (v < N) dinv[v] = rsqrtf((float)cnt[v] + 1.0f);   // +1 self loop
}

__global__ void k_chunk_sum(const int* __restrict__ cnt, int* __restrict__ csum) {
  __shared__ int sp[SCAN_CH / 64];
  int i = blockIdx.x * SCAN_CH + threadIdx.x;
  int v = (i < N) ? cnt[i] : 0;
  for (int off = 32; off > 0; off >>= 1) v += __shfl_down(v, off, 64);
  if ((threadIdx.x & 63) == 0) sp[threadIdx.x >> 6] = v;
  __syncthreads();
  if (threadIdx.x == 0) {
    int s = 0;
    #pragma unroll
    for (int w = 0; w < SCAN_CH / 64; ++w) s += sp[w];
    csum[blockIdx.x] = s;
  }
}

__global__ void k_chunk_scan(const int* __restrict__ csum, int* __restrict__ coff) {
  if (blockIdx.x == 0 && threadIdx.x == 0) {
    int run = 0;
    for (int b = 0; b < NCH; ++b) { coff[b] = run; run += csum[b]; }
    coff[NCH] = run;
  }
}

__global__ void k_scan_final(const int* __restrict__ cnt, const int* __restrict__ coff,
                             int* __restrict__ offv) {
  __shared__ int s[SCAN_CH];
  int tid = threadIdx.x;
  int i = blockIdx.x * SCAN_CH + tid;
  int v = (i < N) ? cnt[i] : 0;
  s[tid] = v;
  __syncthreads();
  for (int st = 1; st < SCAN_CH; st <<= 1) {
    int tv = (tid >= st) ? s[tid - st] : 0;
    __syncthreads();
    s[tid] += tv;
    __syncthreads();
  }
  if (i < N) offv[i] = coff[blockIdx.x] + s[tid] - v;   // exclusive
  if (blockIdx.x == 0 && tid == 0) offv[N] = coff[NCH];
}

// packed CSR entry: one 8B scatter per edge (halves write amplification)
__global__ void k_fill(const int* __restrict__ row, const int* __restrict__ col,
                       const float* __restrict__ dinv, const int* __restrict__ offv,
                       int* __restrict__ cursor, int2* __restrict__ csr) {
  int e = blockIdx.x * 256 + threadIdx.x;
  if (e >= E) return;
  int r = row[e], c = col[e];
  int p = atomicAdd(&cursor[c], 1);
  float nm = dinv[r] * dinv[c];
  csr[offv[c] + p] = make_int2(r, __builtin_bit_cast(int, nm));
}

// ---------------- weight prep (once per call) ----------------
// LSTM: bt[j][k] fp16 (j<512, k<256): k<128 -> W_ih[j][k], else W_hh[j][k-128]
__global__ void k_wprep_lstm(const float* __restrict__ Wih, const float* __restrict__ Whh,
                             _Float16* __restrict__ bt) {
  int idx = blockIdx.x * 256 + threadIdx.x;   // 512*256
  if (idx >= G * 256) return;
  int j = idx >> 8, k = idx & 255;
  float f = (k < H) ? Wih[j * H + k] : Whh[j * H + (k - H)];
  bt[idx] = (_Float16)f;
}

// GCN: bgT[j][k] = W_gcn[k][j]  (128x128) fp16
__global__ void k_wprep_gcn(const float* __restrict__ Wg, _Float16* __restrict__ bgT) {
  int idx = blockIdx.x * 256 + threadIdx.x;   // 128*128
  if (idx >= H * H) return;
  int j = idx >> 7, k = idx & 127;
  bgT[idx] = (_Float16)Wg[k * H + j];
}

// ---------------- GCN GEMM (MFMA fp16): xw = x_t @ W_gcn ----------------
// block 256 thr = 4 waves (2x2) -> 128 rows x 128 cols; K=128 (4 kblocks).
// B (32KB fp16) staged once in LDS, granule-swizzled (slot = g ^ ((j>>1)&3)
// -> 2-way ds_read_b128, free). A fp32 direct load + 1 cvt/elem.
__global__ __launch_bounds__(256) void k_gcn_mfma(const float* __restrict__ X,
                                                  const _Float16* __restrict__ BgT,
                                                  _Float16* __restrict__ xw) {
  __shared__ _Float16 lsB[16384];   // [kb][j][g'] 16B granules, 32KB
  int tid = threadIdx.x;
  int lane = tid & 63, wid = tid >> 6;
  int wr = wid >> 1, wc = wid & 1;
  int rb = blockIdx.x * 128 + wr * 64;
  int cb = wc * 64;
  int lr = lane & 15;
  int g  = lane >> 4;

  #pragma unroll
  for (int i = 0; i < 8; ++i) {           // stage B: 2048 granules of 16B
    int c = i * 256 + tid;
    int kb = c >> 9, j = (c >> 2) & 127, gg = c & 3;
    f16x8 v = *(const f16x8*)&BgT[j * H + kb * 32 + gg * 8];
    int slot = gg ^ ((j >> 1) & 3);
    *(f16x8*)&lsB[kb * 4096 + j * 32 + slot * 8] = v;
  }
  __syncthreads();

  f32x4 acc[4][4];
  #pragma unroll
  for (int mi = 0; mi < 4; ++mi)
    #pragma unroll
    for (int ni = 0; ni < 4; ++ni) acc[mi][ni] = (f32x4)0.0f;

  #pragma unroll
  for (int kb = 0; kb < 4; ++kb) {
    f16x8 bfr[4];
    #pragma unroll
    for (int ni = 0; ni < 4; ++ni) {
      int j = cb + ni * 16 + lr;
      bfr[ni] = *(const f16x8*)&lsB[kb * 4096 + j * 32 + (g ^ ((j >> 1) & 3)) * 8];
    }
    #pragma unroll
    for (int mi = 0; mi < 4; ++mi) {
      int r = rb + mi * 16 + lr;
      r = r < N ? r : N - 1;                     // clamp (pad rows discarded)
      const float* ap = X + (size_t)r * H + kb * 32 + g * 8;
      float4 a0 = *(const float4*)ap;
      float4 a1 = *(const float4*)(ap + 4);
      f16x8 afr;
      afr[0] = (_Float16)a0.x; afr[1] = (_Float16)a0.y;
      afr[2] = (_Float16)a0.z; afr[3] = (_Float16)a0.w;
      afr[4] = (_Float16)a1.x; afr[5] = (_Float16)a1.y;
      afr[6] = (_Float16)a1.z; afr[7] = (_Float16)a1.w;
      #pragma unroll
      for (int ni = 0; ni < 4; ++ni)
        acc[mi][ni] = __builtin_amdgcn_mfma_f32_16x16x32_f16(afr, bfr[ni], acc[mi][ni], 0, 0, 0);
    }
  }
  int orow = (lane >> 4) * 4;
  #pragma unroll
  for (int mi = 0; mi < 4; ++mi)
    #pragma unroll
    for (int ni = 0; ni < 4; ++ni)
      #pragma unroll
      for (int r = 0; r < 4; ++r) {
        int n = rb + mi * 16 + orow + r;
        if (n < N) xw[(size_t)n * H + cb + ni * 16 + lr] = (_Float16)acc[mi][ni][r];
      }
}

// ---------------- aggregation -> emb (fp16 A plane, cols 0..127) ----------------
// Wave per vertex; two 32-lane halves process even/odd edges (f16x4/lane,
// 8B -> 256B/row coalesced), combined via shfl_xor(32). fp32 accumulate.
__global__ __launch_bounds__(256) void k_agg(const _Float16* __restrict__ xw,
                                             const int* __restrict__ offv,
                                             const int2* __restrict__ csr,
                                             const float* __restrict__ dinv,
                                             const float* __restrict__ bg,
                                             _Float16* __restrict__ A) {
  int wid = threadIdx.x >> 6, lane = threadIdx.x & 63;
  int v = blockIdx.x * 4 + wid;          // N % 4 == 0
  int half = lane >> 5, sl = lane & 31;
  int c0 = sl * 4;
  float ax = 0.f, ay = 0.f, az = 0.f, aw = 0.f;
  if (half == 0) {                       // self term once
    float dv = dinv[v];
    float w = dv * dv;
    f16x4 xs = *(const f16x4*)&xw[(size_t)v * H + c0];
    ax = (float)xs.x * w; ay = (float)xs.y * w;
    az = (float)xs.z * w; aw = (float)xs.w * w;
  }
  int e0 = offv[v], e1 = offv[v + 1];
  for (int e = e0 + half; e < e1; e += 2) {
    int2 en = csr[e];
    int s = en.x; float m = __builtin_bit_cast(float, en.y);
    f16x4 x = *(const f16x4*)&xw[(size_t)s * H + c0];
    ax = fmaf((float)x.x, m, ax); ay = fmaf((float)x.y, m, ay);
    az = fmaf((float)x.z, m, az); aw = fmaf((float)x.w, m, aw);
  }
  ax += __shfl_xor(ax, 32, 64);
  ay += __shfl_xor(ay, 32, 64);
  az += __shfl_xor(az, 32, 64);
  aw += __shfl_xor(aw, 32, 64);
  if (half == 0) {
    float4 bb = *(const float4*)&bg[c0];
    f16x4 ov;
    ov.x = (_Float16)fmaxf(ax + bb.x, 0.f);
    ov.y = (_Float16)fmaxf(ay + bb.y, 0.f);
    ov.z = (_Float16)fmaxf(az + bb.z, 0.f);
    ov.w = (_Float16)fmaxf(aw + bb.w, 0.f);
    *(f16x4*)&A[(size_t)v * 256 + c0] = ov;
  }
}

// ---------------- fused gates GEMM + LSTM cell (fp16, global_load_lds) ------
// 256 thr = 4 waves (wr x wc = 2x2). Block tile: 128 rows x 128 logical cols
// (jj = gate*32 + wc*16 + lr -> global j = gate*128 + ch0 + ...), so each wave
// holds (i,f,g,o) of the same (row, channel): cell update in-register.
// K: 8 kblocks of 32 fp16; double-buffered 2x16KB LDS via global_load_lds.
// Row = 64B (4x16B granules); swizzle slot = q ^ ((row>>1)&3) -> 2-way reads
// (free); applied by pre-swizzling the GLOBAL source granule (rule #21).
// h_t written ONLY to the fp16 A-plane (fc reads it from there).
template<bool FIRST>
__global__ __launch_bounds__(256) void k_gates_cell(const _Float16* __restrict__ A,
                                                    const _Float16* __restrict__ Bt,
                                                    const float* __restrict__ bih,
                                                    const float* __restrict__ bhh,
                                                    float* __restrict__ cbuf,
                                                    _Float16* __restrict__ oA) {
  __shared__ _Float16 ls[2][8192];   // 2 x 16KB: [A 8KB | B 8KB]
  const int tid = threadIdx.x;
  const int lane = tid & 63, wid = tid >> 6;
  const int wr = wid >> 1, wc = wid & 1;
  const int lr = lane & 15;
  const int g  = lane >> 4;                 // k granule 0..3 (8 fp16 each)

  // bijective XCD-chunk swizzle (m204)
  int xcd = blockIdx.x & 7, loc = blockIdx.x >> 3;
  int wgid = (xcd < GRR ? xcd * (GQQ + 1) : GRR * (GQQ + 1) + (xcd - GRR) * GQQ) + loc;
  const int rb  = (wgid >> 2) * 128;
  const int ch0 = (wgid & 3) * 32;

  f32x4 acc[4][4];
  #pragma unroll
  for (int mi = 0; mi < 4; ++mi)
    #pragma unroll
    for (int ni = 0; ni < 4; ++ni) acc[mi][ni] = (f32x4)0.0f;

  // stage one 16KB k-block tile (async, no data registers)
  auto stage = [&](int buf, int kb) {
    int ko = kb * 32;
    _Float16* lb = &ls[buf][0];
    #pragma unroll
    for (int i = 0; i < 2; ++i) {
      int c = i * 256 + tid;               // 16B chunk id 0..511
      int row = c >> 2, slot = c & 3;
      int g3 = slot ^ ((row >> 1) & 3);    // pre-swizzled global granule
      size_t ga = (size_t)(rb + row) * 256 + ko + g3 * 8;
      gll16(A + ga, lb + c * 8);
      int j = (row >> 5) * 128 + ch0 + (row & 31);
      size_t gb = (size_t)j * 256 + ko + g3 * 8;
      gll16(Bt + gb, lb + 4096 + c * 8);
    }
  };

  auto compute = [&](int buf) {
    const _Float16* lb = &ls[buf][0];
    f16x8 bfr[4];
    #pragma unroll
    for (int ni = 0; ni < 4; ++ni) {
      int jj = ni * 32 + wc * 16 + lr;
      bfr[ni] = *(const f16x8*)(lb + 4096 + jj * 32 + (g ^ ((jj >> 1) & 3)) * 8);
    }
    #pragma unroll
    for (int mi = 0; mi < 4; ++mi) {
      int rr = wr * 64 + mi * 16 + lr;
      f16x8 afr = *(const f16x8*)(lb + rr * 32 + (g ^ ((rr >> 1) & 3)) * 8);
      #pragma unroll
      for (int ni = 0; ni < 4; ++ni)
        acc[mi][ni] = __builtin_amdgcn_mfma_f32_16x16x32_f16(afr, bfr[ni], acc[mi][ni], 0, 0, 0);
    }
  };

  const int kbs = FIRST ? 4 : 8;            // t=0: h==0, skip upper K half
  stage(0, 0);
  for (int kb = 0; kb < kbs; ++kb) {
    __syncthreads();                        // buf[kb&1] staged; prev reads done
    if (kb + 1 < kbs) stage((kb + 1) & 1, kb + 1);  // async, hides under MFMAs
    compute(kb & 1);
  }

  int ch = ch0 + wc * 16 + lr;
  float bi_ = bih[ch]       + bhh[ch];
  float bf_ = bih[128 + ch] + bhh[128 + ch];
  float bg_ = bih[256 + ch] + bhh[256 + ch];
  float bo_ = bih[384 + ch] + bhh[384 + ch];
  int orow = (lane >> 4) * 4;
  int rbw = rb + wr * 64;
  #pragma unroll
  for (int mi = 0; mi < 4; ++mi) {
    #pragma unroll
    for (int r = 0; r < 4; ++r) {
      int n = rbw + mi * 16 + orow + r;
      if (n >= N) continue;
      float gi = acc[mi][0][r] + bi_;
      float gf = acc[mi][1][r] + bf_;
      float gg = acc[mi][2][r] + bg_;
      float go = acc[mi][3][r] + bo_;
      float si = 1.f / (1.f + expf(-gi));
      float sf = 1.f / (1.f + expf(-gf));
      float so = 1.f / (1.f + expf(-go));
      float tg = tanhf(gg);
      size_t ci = (size_t)n * H + ch;
      float cn = FIRST ? si * tg : fmaf(sf, cbuf[ci], si * tg);
      cbuf[ci] = cn;
      float hn = so * tanhf(cn);
      oA[(size_t)n * 256 + 128 + ch] = (_Float16)hn;
    }
  }
}

// ---------------- FC per step: out[n][t][:] = h[n] @ W_fc^T + b_fc ----------------
// h read from the fp16 A-plane cols 128..255 (written by gates this step).
__global__ __launch_bounds__(256, 3) void k_fc(const _Float16* __restrict__ A,
                                               const float* __restrict__ Wfc,
                                               const float* __restrict__ bfc,
                                               float* __restrict__ outp, int t) {
  __shared__ float hsT[128][68];
  __shared__ float wT[128][36];
  int tid = threadIdx.x;
  int n0 = blockIdx.x * 64;
  for (int i = 0; i < 32; ++i) {
    int idx = i * 256 + tid;
    int r = idx >> 7, k = idx & 127;
    hsT[k][r] = (n0 + r < N) ? (float)A[(size_t)(n0 + r) * 256 + 128 + k] : 0.0f;
  }
  for (int i = 0; i < 16; ++i) {
    int idx = i * 256 + tid;          // 4096 = 32*128
    int oc = idx >> 7, k = idx & 127;
    wT[k][oc] = Wfc[idx];
  }
  __syncthreads();
  int og = tid & 15, rg = tid >> 4;   // 16 oc-groups x 16 row-groups
  int oc0 = og * 2, r0 = rg * 4;
  float acc[4][2] = {};
  #pragma unroll 2
  for (int k = 0; k < 128; ++k) {
    float4 a = *(const float4*)&hsT[k][r0];
    float2 w = *(const float2*)&wT[k][oc0];
    float ar[4] = {a.x, a.y, a.z, a.w};
    #pragma unroll
    for (int i = 0; i < 4; ++i) {
      acc[i][0] = fmaf(ar[i], w.x, acc[i][0]);
      acc[i][1] = fmaf(ar[i], w.y, acc[i][1]);
    }
  }
  float b0 = bfc[oc0], b1 = bfc[oc0 + 1];
  #pragma unroll
  for (int i = 0; i < 4; ++i) {
    int n = n0 + r0 + i;
    if (n < N) {
      size_t ob = ((size_t)n * T + t) * OUTD + oc0;
      outp[ob]     = acc[i][0] + b0;
      outp[ob + 1] = acc[i][1] + b1;
    }
  }
}

// ---------------------------------------------------------------------------

extern "C" void kernel_launch(void* const* d_in, const int* in_sizes, int n_in,
                              void* d_out, int out_size, void* d_ws, size_t ws_size,
                              hipStream_t stream) {
  const float* x_seq = (const float*)d_in[0];
  const int*   eidx  = (const int*)d_in[1];
  const int*   erow  = eidx;          // sources
  const int*   ecol  = eidx + E;      // targets
  const float* W_gcn = (const float*)d_in[2];
  const float* b_gcn = (const float*)d_in[3];
  const float* W_ih  = (const float*)d_in[4];
  const float* W_hh  = (const float*)d_in[5];
  const float* b_ih  = (const float*)d_in[6];
  const float* b_hh  = (const float*)d_in[7];
  const float* W_fc  = (const float*)d_in[8];
  const float* b_fc  = (const float*)d_in[9];
  float* outp = (float*)d_out;

  char* base = (char*)d_ws;
  size_t o = 0;
  auto alloc = [&](size_t bytes) -> void* {
    void* p = base + o;
    o += (bytes + 255) & ~(size_t)255;
    return p;
  };
  int*   cnt      = (int*)  alloc((size_t)N * 4);
  int*   cursor   = (int*)  alloc((size_t)N * 4);
  int*   offv     = (int*)  alloc((size_t)(N + 1) * 4);
  int*   csum     = (int*)  alloc((size_t)(NCH + 1) * 4);
  int*   coff     = (int*)  alloc((size_t)(NCH + 1) * 4);
  float* dinv     = (float*)alloc((size_t)N * 4);
  int2*  csr      = (int2*) alloc((size_t)E * 8);
  _Float16* bt    = (_Float16*)alloc((size_t)G * 256 * 2);
  _Float16* bgT   = (_Float16*)alloc((size_t)H * H * 2);
  _Float16* a0    = (_Float16*)alloc((size_t)NP * 256 * 2);  // [emb | h] fp16, even t
  _Float16* a1    = (_Float16*)alloc((size_t)NP * 256 * 2);  // odd t
  _Float16* xw    = (_Float16*)alloc((size_t)N * H * 2);
  float* cbuf     = (float*)alloc((size_t)N * H * 4);
  (void)ws_size; (void)in_sizes; (void)n_in; (void)out_size;

  _Float16* AP[2] = {a0, a1};

  // only the small CSR counters need zeroing; h/c state handled by the
  // FIRST-step specialization; pad rows only affect discarded output rows.
  hipMemsetAsync(cnt,    0, (size_t)N * 4, stream);
  hipMemsetAsync(cursor, 0, (size_t)N * 4, stream);

  k_count<<<E / 256, 256, 0, stream>>>(ecol, cnt);
  k_dinv<<<(N + 255) / 256, 256, 0, stream>>>(cnt, dinv);
  k_chunk_sum<<<NCH, SCAN_CH, 0, stream>>>(cnt, csum);
  k_chunk_scan<<<1, 64, 0, stream>>>(csum, coff);
  k_scan_final<<<NCH, SCAN_CH, 0, stream>>>(cnt, coff, offv);
  k_fill<<<E / 256, 256, 0, stream>>>(erow, ecol, dinv, offv, cursor, csr);
  k_wprep_lstm<<<(G * 256) / 256, 256, 0, stream>>>(W_ih, W_hh, bt);
  k_wprep_gcn<<<(H * H) / 256, 256, 0, stream>>>(W_gcn, bgT);

  int gblocks = NP / 128;                 // 391, for k_gcn_mfma
  int rblocks = (N + 63) / 64;            // 782, for k_fc
  for (int t = 0; t < T; ++t) {
    int cur = t & 1, nxt = cur ^ 1;
    const float* xt = x_seq + (size_t)t * N * H;
    k_gcn_mfma<<<gblocks, 256, 0, stream>>>(xt, bgT, xw);
    k_agg<<<N / 4, 256, 0, stream>>>(xw, offv, csr, dinv, b_gcn, AP[cur]);
    if (t == 0)
      k_gates_cell<true><<<GNWG, 256, 0, stream>>>(
          AP[cur], bt, b_ih, b_hh, cbuf, AP[nxt]);
    else
      k_gates_cell<false><<<GNWG, 256, 0, stream>>>(
          AP[cur], bt, b_ih, b_hh, cbuf, AP[nxt]);
    k_fc<<<rblocks, 256, 0, stream>>>(AP[nxt], W_fc, b_fc, outp, t);
  }
}

// Round 11
// 1546.617 us; speedup vs baseline: 2.0693x; 1.1452x over previous
//
#include <hip/hip_runtime.h>
#include <cstdint>
#include <cstddef>

// ---------------------------------------------------------------------------
// GCN(1 layer, sym-norm w/ self loops) -> LSTM(1 layer, T=9) -> FC, eval mode
// Round 11: (1) all 9 GCN GEMMs batched into ONE dispatch (xw_all, 115MB,
// L3-resident) — kills 9 launch+tail overheads; (2) k_fc rebuilt on MFMA
// (64r x 32c per wave, fp16 A/W, 32 MFMAs) — was vector-FMA latency-bound.
// agg / gates / CSR unchanged from round 10.
// ---------------------------------------------------------------------------

constexpr int N    = 50000;
constexpr int NP   = 50048;  // padded to 128-row strips (391*128)
constexpr int E    = 1600000;
constexpr int T    = 9;
constexpr int H    = 128;    // F_IN == H == 128
constexpr int G    = 512;    // 4*H (gates i,f,g,o)
constexpr int OUTD = 32;

constexpr int SCAN_CH = 512;
constexpr int NCH = (N + SCAN_CH - 1) / SCAN_CH;   // 98

// gates grid: 391 row-strips x 4 col-quarters
constexpr int GNWG = (NP / 128) * 4;               // 1564
constexpr int GQQ  = GNWG / 8;                     // 195
constexpr int GRR  = GNWG % 8;                     // 4

typedef __attribute__((ext_vector_type(8))) short bf16x8;
typedef __attribute__((ext_vector_type(8))) _Float16 f16x8;
typedef __attribute__((ext_vector_type(4))) float f32x4;
typedef __attribute__((ext_vector_type(4))) _Float16 f16x4;
typedef unsigned short u16;

// async global->LDS, 16B per lane; LDS dest = wave-uniform base + lane*16
__device__ __forceinline__ void gll16(const void* g, void* l) {
  __builtin_amdgcn_global_load_lds(
      (const __attribute__((address_space(1))) void*)g,
      (__attribute__((address_space(3))) void*)l, 16, 0, 0);
}

// ---------------- degree / CSR build ----------------

__global__ void k_count(const int* __restrict__ col, int* __restrict__ cnt) {
  int e = blockIdx.x * 256 + threadIdx.x;
  if (e < E) atomicAdd(&cnt[col[e]], 1);
}

__global__ void k_dinv(const int* __restrict__ cnt, float* __restrict__ dinv) {
  int v = blockIdx.x * 256 + threadIdx.x;
  if (v < N) dinv[v] = rsqrtf((float)cnt[v] + 1.0f);   // +1 self loop
}

__global__ void k_chunk_sum(const int* __restrict__ cnt, int* __restrict__ csum) {
  __shared__ int sp[SCAN_CH / 64];
  int i = blockIdx.x * SCAN_CH + threadIdx.x;
  int v = (i < N) ? cnt[i] : 0;
  for (int off = 32; off > 0; off >>= 1) v += __shfl_down(v, off, 64);
  if ((threadIdx.x & 63) == 0) sp[threadIdx.x >> 6] = v;
  __syncthreads();
  if (threadIdx.x == 0) {
    int s = 0;
    #pragma unroll
    for (int w = 0; w < SCAN_CH / 64; ++w) s += sp[w];
    csum[blockIdx.x] = s;
  }
}

__global__ void k_chunk_scan(const int* __restrict__ csum, int* __restrict__ coff) {
  if (blockIdx.x == 0 && threadIdx.x == 0) {
    int run = 0;
    for (int b = 0; b < NCH; ++b) { coff[b] = run; run += csum[b]; }
    coff[NCH] = run;
  }
}

__global__ void k_scan_final(const int* __restrict__ cnt, const int* __restrict__ coff,
                             int* __restrict__ offv) {
  __shared__ int s[SCAN_CH];
  int tid = threadIdx.x;
  int i = blockIdx.x * SCAN_CH + tid;
  int v = (i < N) ? cnt[i] : 0;
  s[tid] = v;
  __syncthreads();
  for (int st = 1; st < SCAN_CH; st <<= 1) {
    int tv = (tid >= st) ? s[tid - st] : 0;
    __syncthreads();
    s[tid] += tv;
    __syncthreads();
  }
  if (i < N) offv[i] = coff[blockIdx.x] + s[tid] - v;   // exclusive
  if (blockIdx.x == 0 && tid == 0) offv[N] = coff[NCH];
}

// packed CSR entry: one 8B scatter per edge (halves write amplification)
__global__ void k_fill(const int* __restrict__ row, const int* __restrict__ col,
                       const float* __restrict__ dinv, const int* __restrict__ offv,
                       int* __restrict__ cursor, int2* __restrict__ csr) {
  int e = blockIdx.x * 256 + threadIdx.x;
  if (e >= E) return;
  int r = row[e], c = col[e];
  int p = atomicAdd(&cursor[c], 1);
  float nm = dinv[r] * dinv[c];
  csr[offv[c] + p] = make_int2(r, __builtin_bit_cast(int, nm));
}

// ---------------- weight prep (once per call) ----------------
// LSTM: bt[j][k] fp16 (j<512, k<256): k<128 -> W_ih[j][k], else W_hh[j][k-128]
__global__ void k_wprep_lstm(const float* __restrict__ Wih, const float* __restrict__ Whh,
                             _Float16* __restrict__ bt) {
  int idx = blockIdx.x * 256 + threadIdx.x;   // 512*256
  if (idx >= G * 256) return;
  int j = idx >> 8, k = idx & 255;
  float f = (k < H) ? Wih[j * H + k] : Whh[j * H + (k - H)];
  bt[idx] = (_Float16)f;
}

// GCN: bgT[j][k] = W_gcn[k][j]  (128x128) fp16
__global__ void k_wprep_gcn(const float* __restrict__ Wg, _Float16* __restrict__ bgT) {
  int idx = blockIdx.x * 256 + threadIdx.x;   // 128*128
  if (idx >= H * H) return;
  int j = idx >> 7, k = idx & 127;
  bgT[idx] = (_Float16)Wg[k * H + j];
}

// FC: wfc16[j][k] fp16 copy of W_fc (32x128)
__global__ void k_wprep_fc(const float* __restrict__ Wfc, _Float16* __restrict__ w16) {
  int idx = blockIdx.x * 256 + threadIdx.x;   // 32*128
  if (idx < OUTD * H) w16[idx] = (_Float16)Wfc[idx];
}

// ---------------- GCN GEMM (MFMA fp16), ALL timesteps: xw_all[t] = x_t @ W ----
// grid (391, 9); block 256 thr = 4 waves (2x2) -> 128 rows x 128 cols.
// B (32KB fp16) staged once in LDS, granule-swizzled (slot = g ^ ((j>>1)&3)
// -> 2-way ds_read_b128, free). A fp32 direct load + 1 cvt/elem.
__global__ __launch_bounds__(256) void k_gcn_all(const float* __restrict__ Xall,
                                                 const _Float16* __restrict__ BgT,
                                                 _Float16* __restrict__ xw_all) {
  __shared__ _Float16 lsB[16384];   // [kb][j][g'] 16B granules, 32KB
  const float* X = Xall + (size_t)blockIdx.y * N * H;
  _Float16* xw = xw_all + (size_t)blockIdx.y * N * H;
  int tid = threadIdx.x;
  int lane = tid & 63, wid = tid >> 6;
  int wr = wid >> 1, wc = wid & 1;
  int rb = blockIdx.x * 128 + wr * 64;
  int cb = wc * 64;
  int lr = lane & 15;
  int g  = lane >> 4;

  #pragma unroll
  for (int i = 0; i < 8; ++i) {           // stage B: 2048 granules of 16B
    int c = i * 256 + tid;
    int kb = c >> 9, j = (c >> 2) & 127, gg = c & 3;
    f16x8 v = *(const f16x8*)&BgT[j * H + kb * 32 + gg * 8];
    int slot = gg ^ ((j >> 1) & 3);
    *(f16x8*)&lsB[kb * 4096 + j * 32 + slot * 8] = v;
  }
  __syncthreads();

  f32x4 acc[4][4];
  #pragma unroll
  for (int mi = 0; mi < 4; ++mi)
    #pragma unroll
    for (int ni = 0; ni < 4; ++ni) acc[mi][ni] = (f32x4)0.0f;

  #pragma unroll
  for (int kb = 0; kb < 4; ++kb) {
    f16x8 bfr[4];
    #pragma unroll
    for (int ni = 0; ni < 4; ++ni) {
      int j = cb + ni * 16 + lr;
      bfr[ni] = *(const f16x8*)&lsB[kb * 4096 + j * 32 + (g ^ ((j >> 1) & 3)) * 8];
    }
    #pragma unroll
    for (int mi = 0; mi < 4; ++mi) {
      int r = rb + mi * 16 + lr;
      r = r < N ? r : N - 1;                     // clamp (pad rows discarded)
      const float* ap = X + (size_t)r * H + kb * 32 + g * 8;
      float4 a0 = *(const float4*)ap;
      float4 a1 = *(const float4*)(ap + 4);
      f16x8 afr;
      afr[0] = (_Float16)a0.x; afr[1] = (_Float16)a0.y;
      afr[2] = (_Float16)a0.z; afr[3] = (_Float16)a0.w;
      afr[4] = (_Float16)a1.x; afr[5] = (_Float16)a1.y;
      afr[6] = (_Float16)a1.z; afr[7] = (_Float16)a1.w;
      #pragma unroll
      for (int ni = 0; ni < 4; ++ni)
        acc[mi][ni] = __builtin_amdgcn_mfma_f32_16x16x32_f16(afr, bfr[ni], acc[mi][ni], 0, 0, 0);
    }
  }
  int orow = (lane >> 4) * 4;
  #pragma unroll
  for (int mi = 0; mi < 4; ++mi)
    #pragma unroll
    for (int ni = 0; ni < 4; ++ni)
      #pragma unroll
      for (int r = 0; r < 4; ++r) {
        int n = rb + mi * 16 + orow + r;
        if (n < N) xw[(size_t)n * H + cb + ni * 16 + lr] = (_Float16)acc[mi][ni][r];
      }
}

// ---------------- aggregation -> emb (fp16 A plane, cols 0..127) ----------------
// Wave per vertex; two 32-lane halves process even/odd edges (f16x4/lane,
// 8B -> 256B/row coalesced), combined via shfl_xor(32). fp32 accumulate.
__global__ __launch_bounds__(256) void k_agg(const _Float16* __restrict__ xw,
                                             const int* __restrict__ offv,
                                             const int2* __restrict__ csr,
                                             const float* __restrict__ dinv,
                                             const float* __restrict__ bg,
                                             _Float16* __restrict__ A) {
  int wid = threadIdx.x >> 6, lane = threadIdx.x & 63;
  int v = blockIdx.x * 4 + wid;          // N % 4 == 0
  int half = lane >> 5, sl = lane & 31;
  int c0 = sl * 4;
  float ax = 0.f, ay = 0.f, az = 0.f, aw = 0.f;
  if (half == 0) {                       // self term once
    float dv = dinv[v];
    float w = dv * dv;
    f16x4 xs = *(const f16x4*)&xw[(size_t)v * H + c0];
    ax = (float)xs.x * w; ay = (float)xs.y * w;
    az = (float)xs.z * w; aw = (float)xs.w * w;
  }
  int e0 = offv[v], e1 = offv[v + 1];
  for (int e = e0 + half; e < e1; e += 2) {
    int2 en = csr[e];
    int s = en.x; float m = __builtin_bit_cast(float, en.y);
    f16x4 x = *(const f16x4*)&xw[(size_t)s * H + c0];
    ax = fmaf((float)x.x, m, ax); ay = fmaf((float)x.y, m, ay);
    az = fmaf((float)x.z, m, az); aw = fmaf((float)x.w, m, aw);
  }
  ax += __shfl_xor(ax, 32, 64);
  ay += __shfl_xor(ay, 32, 64);
  az += __shfl_xor(az, 32, 64);
  aw += __shfl_xor(aw, 32, 64);
  if (half == 0) {
    float4 bb = *(const float4*)&bg[c0];
    f16x4 ov;
    ov.x = (_Float16)fmaxf(ax + bb.x, 0.f);
    ov.y = (_Float16)fmaxf(ay + bb.y, 0.f);
    ov.z = (_Float16)fmaxf(az + bb.z, 0.f);
    ov.w = (_Float16)fmaxf(aw + bb.w, 0.f);
    *(f16x4*)&A[(size_t)v * 256 + c0] = ov;
  }
}

// ---------------- fused gates GEMM + LSTM cell (fp16, global_load_lds) ------
// 256 thr = 4 waves (wr x wc = 2x2). Block tile: 128 rows x 128 logical cols
// (jj = gate*32 + wc*16 + lr -> global j = gate*128 + ch0 + ...), so each wave
// holds (i,f,g,o) of the same (row, channel): cell update in-register.
// K: 8 kblocks of 32 fp16; double-buffered 2x16KB LDS via global_load_lds.
// Row = 64B (4x16B granules); swizzle slot = q ^ ((row>>1)&3) -> 2-way reads
// (free); applied by pre-swizzling the GLOBAL source granule (rule #21).
// h_t written ONLY to the fp16 A-plane (fc reads it from there).
template<bool FIRST>
__global__ __launch_bounds__(256) void k_gates_cell(const _Float16* __restrict__ A,
                                                    const _Float16* __restrict__ Bt,
                                                    const float* __restrict__ bih,
                                                    const float* __restrict__ bhh,
                                                    float* __restrict__ cbuf,
                                                    _Float16* __restrict__ oA) {
  __shared__ _Float16 ls[2][8192];   // 2 x 16KB: [A 8KB | B 8KB]
  const int tid = threadIdx.x;
  const int lane = tid & 63, wid = tid >> 6;
  const int wr = wid >> 1, wc = wid & 1;
  const int lr = lane & 15;
  const int g  = lane >> 4;                 // k granule 0..3 (8 fp16 each)

  // bijective XCD-chunk swizzle (m204)
  int xcd = blockIdx.x & 7, loc = blockIdx.x >> 3;
  int wgid = (xcd < GRR ? xcd * (GQQ + 1) : GRR * (GQQ + 1) + (xcd - GRR) * GQQ) + loc;
  const int rb  = (wgid >> 2) * 128;
  const int ch0 = (wgid & 3) * 32;

  f32x4 acc[4][4];
  #pragma unroll
  for (int mi = 0; mi < 4; ++mi)
    #pragma unroll
    for (int ni = 0; ni < 4; ++ni) acc[mi][ni] = (f32x4)0.0f;

  // stage one 16KB k-block tile (async, no data registers)
  auto stage = [&](int buf, int kb) {
    int ko = kb * 32;
    _Float16* lb = &ls[buf][0];
    #pragma unroll
    for (int i = 0; i < 2; ++i) {
      int c = i * 256 + tid;               // 16B chunk id 0..511
      int row = c >> 2, slot = c & 3;
      int g3 = slot ^ ((row >> 1) & 3);    // pre-swizzled global granule
      size_t ga = (size_t)(rb + row) * 256 + ko + g3 * 8;
      gll16(A + ga, lb + c * 8);
      int j = (row >> 5) * 128 + ch0 + (row & 31);
      size_t gb = (size_t)j * 256 + ko + g3 * 8;
      gll16(Bt + gb, lb + 4096 + c * 8);
    }
  };

  auto compute = [&](int buf) {
    const _Float16* lb = &ls[buf][0];
    f16x8 bfr[4];
    #pragma unroll
    for (int ni = 0; ni < 4; ++ni) {
      int jj = ni * 32 + wc * 16 + lr;
      bfr[ni] = *(const f16x8*)(lb + 4096 + jj * 32 + (g ^ ((jj >> 1) & 3)) * 8);
    }
    #pragma unroll
    for (int mi = 0; mi < 4; ++mi) {
      int rr = wr * 64 + mi * 16 + lr;
      f16x8 afr = *(const f16x8*)(lb + rr * 32 + (g ^ ((rr >> 1) & 3)) * 8);
      #pragma unroll
      for (int ni = 0; ni < 4; ++ni)
        acc[mi][ni] = __builtin_amdgcn_mfma_f32_16x16x32_f16(afr, bfr[ni], acc[mi][ni], 0, 0, 0);
    }
  };

  const int kbs = FIRST ? 4 : 8;            // t=0: h==0, skip upper K half
  stage(0, 0);
  for (int kb = 0; kb < kbs; ++kb) {
    __syncthreads();                        // buf[kb&1] staged; prev reads done
    if (kb + 1 < kbs) stage((kb + 1) & 1, kb + 1);  // async, hides under MFMAs
    compute(kb & 1);
  }

  int ch = ch0 + wc * 16 + lr;
  float bi_ = bih[ch]       + bhh[ch];
  float bf_ = bih[128 + ch] + bhh[128 + ch];
  float bg_ = bih[256 + ch] + bhh[256 + ch];
  float bo_ = bih[384 + ch] + bhh[384 + ch];
  int orow = (lane >> 4) * 4;
  int rbw = rb + wr * 64;
  #pragma unroll
  for (int mi = 0; mi < 4; ++mi) {
    #pragma unroll
    for (int r = 0; r < 4; ++r) {
      int n = rbw + mi * 16 + orow + r;
      if (n >= N) continue;
      float gi = acc[mi][0][r] + bi_;
      float gf = acc[mi][1][r] + bf_;
      float gg = acc[mi][2][r] + bg_;
      float go = acc[mi][3][r] + bo_;
      float si = 1.f / (1.f + expf(-gi));
      float sf = 1.f / (1.f + expf(-gf));
      float so = 1.f / (1.f + expf(-go));
      float tg = tanhf(gg);
      size_t ci = (size_t)n * H + ch;
      float cn = FIRST ? si * tg : fmaf(sf, cbuf[ci], si * tg);
      cbuf[ci] = cn;
      float hn = so * tanhf(cn);
      oA[(size_t)n * 256 + 128 + ch] = (_Float16)hn;
    }
  }
}

// ---------------- FC (MFMA): out[n][t][:] = h[n] @ W_fc^T + b_fc ----------------
// h fp16 from A-plane cols 128..255; Wfc fp16 [32][128]. Wave = 64 rows x 32
// cols (mi=4, ni=2, 4 kblocks -> 32 MFMAs). Block 256 thr = 4 waves = 256 rows.
__global__ __launch_bounds__(256) void k_fc_mfma(const _Float16* __restrict__ A,
                                                 const _Float16* __restrict__ w16,
                                                 const float* __restrict__ bfc,
                                                 float* __restrict__ outp, int t) {
  int lane = threadIdx.x & 63, wid = threadIdx.x >> 6;
  int rb = blockIdx.x * 256 + wid * 64;
  int lr = lane & 15, g = lane >> 4;
  f32x4 acc[4][2];
  #pragma unroll
  for (int mi = 0; mi < 4; ++mi) { acc[mi][0] = (f32x4)0.0f; acc[mi][1] = (f32x4)0.0f; }

  #pragma unroll
  for (int kb = 0; kb < 4; ++kb) {
    int ko = kb * 32 + g * 8;
    f16x8 bfr[2];
    #pragma unroll
    for (int ni = 0; ni < 2; ++ni)
      bfr[ni] = *(const f16x8*)&w16[(ni * 16 + lr) * H + ko];
    #pragma unroll
    for (int mi = 0; mi < 4; ++mi) {
      int n = rb + mi * 16 + lr;
      n = n < N ? n : N - 1;               // clamp (pad rows discarded)
      f16x8 afr = *(const f16x8*)&A[(size_t)n * 256 + 128 + ko];
      #pragma unroll
      for (int ni = 0; ni < 2; ++ni)
        acc[mi][ni] = __builtin_amdgcn_mfma_f32_16x16x32_f16(afr, bfr[ni], acc[mi][ni], 0, 0, 0);
    }
  }
  int orow = g * 4;
  #pragma unroll
  for (int ni = 0; ni < 2; ++ni) {
    int oc = ni * 16 + lr;
    float bb = bfc[oc];
    #pragma unroll
    for (int mi = 0; mi < 4; ++mi)
      #pragma unroll
      for (int r = 0; r < 4; ++r) {
        int n = rb + mi * 16 + orow + r;
        if (n < N) outp[((size_t)n * T + t) * OUTD + oc] = acc[mi][ni][r] + bb;
      }
  }
}

// ---------------------------------------------------------------------------

extern "C" void kernel_launch(void* const* d_in, const int* in_sizes, int n_in,
                              void* d_out, int out_size, void* d_ws, size_t ws_size,
                              hipStream_t stream) {
  const float* x_seq = (const float*)d_in[0];
  const int*   eidx  = (const int*)d_in[1];
  const int*   erow  = eidx;          // sources
  const int*   ecol  = eidx + E;      // targets
  const float* W_gcn = (const float*)d_in[2];
  const float* b_gcn = (const float*)d_in[3];
  const float* W_ih  = (const float*)d_in[4];
  const float* W_hh  = (const float*)d_in[5];
  const float* b_ih  = (const float*)d_in[6];
  const float* b_hh  = (const float*)d_in[7];
  const float* W_fc  = (const float*)d_in[8];
  const float* b_fc  = (const float*)d_in[9];
  float* outp = (float*)d_out;

  char* base = (char*)d_ws;
  size_t o = 0;
  auto alloc = [&](size_t bytes) -> void* {
    void* p = base + o;
    o += (bytes + 255) & ~(size_t)255;
    return p;
  };
  int*   cnt      = (int*)  alloc((size_t)N * 4);
  int*   cursor   = (int*)  alloc((size_t)N * 4);
  int*   offv     = (int*)  alloc((size_t)(N + 1) * 4);
  int*   csum     = (int*)  alloc((size_t)(NCH + 1) * 4);
  int*   coff     = (int*)  alloc((size_t)(NCH + 1) * 4);
  float* dinv     = (float*)alloc((size_t)N * 4);
  int2*  csr      = (int2*) alloc((size_t)E * 8);
  _Float16* bt    = (_Float16*)alloc((size_t)G * 256 * 2);
  _Float16* bgT   = (_Float16*)alloc((size_t)H * H * 2);
  _Float16* wfc16 = (_Float16*)alloc((size_t)OUTD * H * 2);
  _Float16* a0    = (_Float16*)alloc((size_t)NP * 256 * 2);  // [emb | h] fp16, even t
  _Float16* a1    = (_Float16*)alloc((size_t)NP * 256 * 2);  // odd t
  _Float16* xw_all= (_Float16*)alloc((size_t)T * N * H * 2); // 115 MB, L3-resident
  float* cbuf     = (float*)alloc((size_t)N * H * 4);
  (void)ws_size; (void)in_sizes; (void)n_in; (void)out_size;

  _Float16* AP[2] = {a0, a1};

  // only the small CSR counters need zeroing; h/c state handled by the
  // FIRST-step specialization; pad rows only affect discarded output rows.
  hipMemsetAsync(cnt,    0, (size_t)N * 4, stream);
  hipMemsetAsync(cursor, 0, (size_t)N * 4, stream);

  k_count<<<E / 256, 256, 0, stream>>>(ecol, cnt);
  k_dinv<<<(N + 255) / 256, 256, 0, stream>>>(cnt, dinv);
  k_chunk_sum<<<NCH, SCAN_CH, 0, stream>>>(cnt, csum);
  k_chunk_scan<<<1, 64, 0, stream>>>(csum, coff);
  k_scan_final<<<NCH, SCAN_CH, 0, stream>>>(cnt, coff, offv);
  k_fill<<<E / 256, 256, 0, stream>>>(erow, ecol, dinv, offv, cursor, csr);
  k_wprep_lstm<<<(G * 256) / 256, 256, 0, stream>>>(W_ih, W_hh, bt);
  k_wprep_gcn<<<(H * H) / 256, 256, 0, stream>>>(W_gcn, bgT);
  k_wprep_fc<<<(OUTD * H + 255) / 256, 256, 0, stream>>>(W_fc, wfc16);

  // all 9 GCN GEMMs in one dispatch (no LSTM dependence)
  k_gcn_all<<<dim3(NP / 128, T), 256, 0, stream>>>(x_seq, bgT, xw_all);

  int fcblocks = (NP + 255) / 256;        // 196
  for (int t = 0; t < T; ++t) {
    int cur = t & 1, nxt = cur ^ 1;
    k_agg<<<N / 4, 256, 0, stream>>>(xw_all + (size_t)t * N * H, offv, csr, dinv,
                                     b_gcn, AP[cur]);
    if (t == 0)
      k_gates_cell<true><<<GNWG, 256, 0, stream>>>(
          AP[cur], bt, b_ih, b_hh, cbuf, AP[nxt]);
    else
      k_gates_cell<false><<<GNWG, 256, 0, stream>>>(
          AP[cur], bt, b_ih, b_hh, cbuf, AP[nxt]);
    k_fc_mfma<<<fcblocks, 256, 0, stream>>>(AP[nxt], wfc16, b_fc, outp, t);
  }
}

// Round 12
// 1243.999 us; speedup vs baseline: 2.5727x; 1.2433x over previous
//
#include <hip/hip_runtime.h>
#include <cstdint>
#include <cstddef>

// ---------------------------------------------------------------------------
// GCN(1 layer, sym-norm w/ self loops) -> LSTM(1 layer, T=9) -> FC, eval mode
// Round 12: whole aggregation phase in ONE dispatch (k_agg_all: per vertex,
// read edge meta once, 9 independent gathers -> 9 emb rows). emb_all[t] and
// compact h ping-pong planes [N][128]; gates stages emb/h from split buffers
// (kb<4 -> emb_all[t], kb>=4 -> h). gcn_all / gates pipeline / fc unchanged.
// ---------------------------------------------------------------------------

constexpr int N    = 50000;
constexpr int NP   = 50048;  // padded to 128-row strips (391*128)
constexpr int E    = 1600000;
constexpr int T    = 9;
constexpr int H    = 128;    // F_IN == H == 128
constexpr int G    = 512;    // 4*H (gates i,f,g,o)
constexpr int OUTD = 32;

constexpr int SCAN_CH = 512;
constexpr int NCH = (N + SCAN_CH - 1) / SCAN_CH;   // 98

// gates grid: 391 row-strips x 4 col-quarters
constexpr int GNWG = (NP / 128) * 4;               // 1564
constexpr int GQQ  = GNWG / 8;                     // 195
constexpr int GRR  = GNWG % 8;                     // 4

typedef __attribute__((ext_vector_type(8))) _Float16 f16x8;
typedef __attribute__((ext_vector_type(4))) float f32x4;
typedef __attribute__((ext_vector_type(4))) _Float16 f16x4;

// async global->LDS, 16B per lane; LDS dest = wave-uniform base + lane*16
__device__ __forceinline__ void gll16(const void* g, void* l) {
  __builtin_amdgcn_global_load_lds(
      (const __attribute__((address_space(1))) void*)g,
      (__attribute__((address_space(3))) void*)l, 16, 0, 0);
}

// ---------------- degree / CSR build ----------------

__global__ void k_count(const int* __restrict__ col, int* __restrict__ cnt) {
  int e = blockIdx.x * 256 + threadIdx.x;
  if (e < E) atomicAdd(&cnt[col[e]], 1);
}

__global__ void k_dinv(const int* __restrict__ cnt, float* __restrict__ dinv) {
  int v = blockIdx.x * 256 + threadIdx.x;
  if (v < N) dinv[v] = rsqrtf((float)cnt[v] + 1.0f);   // +1 self loop
}

__global__ void k_chunk_sum(const int* __restrict__ cnt, int* __restrict__ csum) {
  __shared__ int sp[SCAN_CH / 64];
  int i = blockIdx.x * SCAN_CH + threadIdx.x;
  int v = (i < N) ? cnt[i] : 0;
  for (int off = 32; off > 0; off >>= 1) v += __shfl_down(v, off, 64);
  if ((threadIdx.x & 63) == 0) sp[threadIdx.x >> 6] = v;
  __syncthreads();
  if (threadIdx.x == 0) {
    int s = 0;
    #pragma unroll
    for (int w = 0; w < SCAN_CH / 64; ++w) s += sp[w];
    csum[blockIdx.x] = s;
  }
}

__global__ void k_chunk_scan(const int* __restrict__ csum, int* __restrict__ coff) {
  if (blockIdx.x == 0 && threadIdx.x == 0) {
    int run = 0;
    for (int b = 0; b < NCH; ++b) { coff[b] = run; run += csum[b]; }
    coff[NCH] = run;
  }
}

__global__ void k_scan_final(const int* __restrict__ cnt, const int* __restrict__ coff,
                             int* __restrict__ offv) {
  __shared__ int s[SCAN_CH];
  int tid = threadIdx.x;
  int i = blockIdx.x * SCAN_CH + tid;
  int v = (i < N) ? cnt[i] : 0;
  s[tid] = v;
  __syncthreads();
  for (int st = 1; st < SCAN_CH; st <<= 1) {
    int tv = (tid >= st) ? s[tid - st] : 0;
    __syncthreads();
    s[tid] += tv;
    __syncthreads();
  }
  if (i < N) offv[i] = coff[blockIdx.x] + s[tid] - v;   // exclusive
  if (blockIdx.x == 0 && tid == 0) offv[N] = coff[NCH];
}

// packed CSR entry: one 8B scatter per edge (halves write amplification)
__global__ void k_fill(const int* __restrict__ row, const int* __restrict__ col,
                       const float* __restrict__ dinv, const int* __restrict__ offv,
                       int* __restrict__ cursor, int2* __restrict__ csr) {
  int e = blockIdx.x * 256 + threadIdx.x;
  if (e >= E) return;
  int r = row[e], c = col[e];
  int p = atomicAdd(&cursor[c], 1);
  float nm = dinv[r] * dinv[c];
  csr[offv[c] + p] = make_int2(r, __builtin_bit_cast(int, nm));
}

// ---------------- weight prep (once per call) ----------------
// LSTM: bt[j][k] fp16 (j<512, k<256): k<128 -> W_ih[j][k], else W_hh[j][k-128]
__global__ void k_wprep_lstm(const float* __restrict__ Wih, const float* __restrict__ Whh,
                             _Float16* __restrict__ bt) {
  int idx = blockIdx.x * 256 + threadIdx.x;   // 512*256
  if (idx >= G * 256) return;
  int j = idx >> 8, k = idx & 255;
  float f = (k < H) ? Wih[j * H + k] : Whh[j * H + (k - H)];
  bt[idx] = (_Float16)f;
}

// GCN: bgT[j][k] = W_gcn[k][j]  (128x128) fp16
__global__ void k_wprep_gcn(const float* __restrict__ Wg, _Float16* __restrict__ bgT) {
  int idx = blockIdx.x * 256 + threadIdx.x;   // 128*128
  if (idx >= H * H) return;
  int j = idx >> 7, k = idx & 127;
  bgT[idx] = (_Float16)Wg[k * H + j];
}

// FC: wfc16[j][k] fp16 copy of W_fc (32x128)
__global__ void k_wprep_fc(const float* __restrict__ Wfc, _Float16* __restrict__ w16) {
  int idx = blockIdx.x * 256 + threadIdx.x;   // 32*128
  if (idx < OUTD * H) w16[idx] = (_Float16)Wfc[idx];
}

// ---------------- GCN GEMM (MFMA fp16), ALL timesteps: xw_all[t] = x_t @ W ----
// grid (391, 9); block 256 thr = 4 waves (2x2) -> 128 rows x 128 cols.
__global__ __launch_bounds__(256) void k_gcn_all(const float* __restrict__ Xall,
                                                 const _Float16* __restrict__ BgT,
                                                 _Float16* __restrict__ xw_all) {
  __shared__ _Float16 lsB[16384];   // [kb][j][g'] 16B granules, 32KB
  const float* X = Xall + (size_t)blockIdx.y * N * H;
  _Float16* xw = xw_all + (size_t)blockIdx.y * N * H;
  int tid = threadIdx.x;
  int lane = tid & 63, wid = tid >> 6;
  int wr = wid >> 1, wc = wid & 1;
  int rb = blockIdx.x * 128 + wr * 64;
  int cb = wc * 64;
  int lr = lane & 15;
  int g  = lane >> 4;

  #pragma unroll
  for (int i = 0; i < 8; ++i) {           // stage B: 2048 granules of 16B
    int c = i * 256 + tid;
    int kb = c >> 9, j = (c >> 2) & 127, gg = c & 3;
    f16x8 v = *(const f16x8*)&BgT[j * H + kb * 32 + gg * 8];
    int slot = gg ^ ((j >> 1) & 3);
    *(f16x8*)&lsB[kb * 4096 + j * 32 + slot * 8] = v;
  }
  __syncthreads();

  f32x4 acc[4][4];
  #pragma unroll
  for (int mi = 0; mi < 4; ++mi)
    #pragma unroll
    for (int ni = 0; ni < 4; ++ni) acc[mi][ni] = (f32x4)0.0f;

  #pragma unroll
  for (int kb = 0; kb < 4; ++kb) {
    f16x8 bfr[4];
    #pragma unroll
    for (int ni = 0; ni < 4; ++ni) {
      int j = cb + ni * 16 + lr;
      bfr[ni] = *(const f16x8*)&lsB[kb * 4096 + j * 32 + (g ^ ((j >> 1) & 3)) * 8];
    }
    #pragma unroll
    for (int mi = 0; mi < 4; ++mi) {
      int r = rb + mi * 16 + lr;
      r = r < N ? r : N - 1;                     // clamp (pad rows discarded)
      const float* ap = X + (size_t)r * H + kb * 32 + g * 8;
      float4 a0 = *(const float4*)ap;
      float4 a1 = *(const float4*)(ap + 4);
      f16x8 afr;
      afr[0] = (_Float16)a0.x; afr[1] = (_Float16)a0.y;
      afr[2] = (_Float16)a0.z; afr[3] = (_Float16)a0.w;
      afr[4] = (_Float16)a1.x; afr[5] = (_Float16)a1.y;
      afr[6] = (_Float16)a1.z; afr[7] = (_Float16)a1.w;
      #pragma unroll
      for (int ni = 0; ni < 4; ++ni)
        acc[mi][ni] = __builtin_amdgcn_mfma_f32_16x16x32_f16(afr, bfr[ni], acc[mi][ni], 0, 0, 0);
    }
  }
  int orow = (lane >> 4) * 4;
  #pragma unroll
  for (int mi = 0; mi < 4; ++mi)
    #pragma unroll
    for (int ni = 0; ni < 4; ++ni)
      #pragma unroll
      for (int r = 0; r < 4; ++r) {
        int n = rb + mi * 16 + orow + r;
        if (n < N) xw[(size_t)n * H + cb + ni * 16 + lr] = (_Float16)acc[mi][ni][r];
      }
}

// ---------------- aggregation, ALL timesteps in one dispatch ----------------
// Wave per vertex; two 32-lane halves process even/odd edges. Edge metadata
// read ONCE, then 9 independent f16x4 gathers (one per t) -> 9x MLP.
// acc[9][4] fp32 (statically unrolled). emb written to emb_all[t][N][128].
__global__ __launch_bounds__(256) void k_agg_all(const _Float16* __restrict__ xw_all,
                                                 const int* __restrict__ offv,
                                                 const int2* __restrict__ csr,
                                                 const float* __restrict__ dinv,
                                                 const float* __restrict__ bg,
                                                 _Float16* __restrict__ emb_all) {
  int wid = threadIdx.x >> 6, lane = threadIdx.x & 63;
  int v = blockIdx.x * 4 + wid;          // N % 4 == 0
  int half = lane >> 5, sl = lane & 31;
  int c0 = sl * 4;
  float acc[T][4];
  #pragma unroll
  for (int t = 0; t < T; ++t) {
    acc[t][0] = 0.f; acc[t][1] = 0.f; acc[t][2] = 0.f; acc[t][3] = 0.f;
  }
  size_t vrow = (size_t)v * H + c0;
  if (half == 0) {                       // self term once
    float dv = dinv[v];
    float w = dv * dv;
    #pragma unroll
    for (int t = 0; t < T; ++t) {
      f16x4 xs = *(const f16x4*)&xw_all[(size_t)t * N * H + vrow];
      acc[t][0] = (float)xs.x * w; acc[t][1] = (float)xs.y * w;
      acc[t][2] = (float)xs.z * w; acc[t][3] = (float)xs.w * w;
    }
  }
  int e0 = offv[v], e1 = offv[v + 1];
  for (int e = e0 + half; e < e1; e += 2) {
    int2 en = csr[e];
    int s = en.x; float m = __builtin_bit_cast(float, en.y);
    const _Float16* xp = xw_all + (size_t)s * H + c0;
    #pragma unroll
    for (int t = 0; t < T; ++t) {
      f16x4 x = *(const f16x4*)(xp + (size_t)t * N * H);
      acc[t][0] = fmaf((float)x.x, m, acc[t][0]);
      acc[t][1] = fmaf((float)x.y, m, acc[t][1]);
      acc[t][2] = fmaf((float)x.z, m, acc[t][2]);
      acc[t][3] = fmaf((float)x.w, m, acc[t][3]);
    }
  }
  #pragma unroll
  for (int t = 0; t < T; ++t) {
    acc[t][0] += __shfl_xor(acc[t][0], 32, 64);
    acc[t][1] += __shfl_xor(acc[t][1], 32, 64);
    acc[t][2] += __shfl_xor(acc[t][2], 32, 64);
    acc[t][3] += __shfl_xor(acc[t][3], 32, 64);
  }
  if (half == 0) {
    float4 bb = *(const float4*)&bg[c0];
    #pragma unroll
    for (int t = 0; t < T; ++t) {
      f16x4 ov;
      ov.x = (_Float16)fmaxf(acc[t][0] + bb.x, 0.f);
      ov.y = (_Float16)fmaxf(acc[t][1] + bb.y, 0.f);
      ov.z = (_Float16)fmaxf(acc[t][2] + bb.z, 0.f);
      ov.w = (_Float16)fmaxf(acc[t][3] + bb.w, 0.f);
      *(f16x4*)&emb_all[(size_t)t * N * H + vrow] = ov;
    }
  }
}

// ---------------- fused gates GEMM + LSTM cell (fp16, global_load_lds) ------
// 256 thr = 4 waves (wr x wc = 2x2). Block tile: 128 rows x 128 logical cols
// (jj = gate*32 + wc*16 + lr -> global j = gate*128 + ch0 + ...), so each wave
// holds (i,f,g,o) of the same (row, channel): cell update in-register.
// K: 8 kblocks of 32 fp16 — kb 0..3 stage emb_t[N][128], kb 4..7 stage
// h_{t-1}[N][128] (uniform branch). Double-buffered 2x16KB LDS via
// global_load_lds; granule swizzle slot = q ^ ((row>>1)&3) (2-way, free),
// applied by pre-swizzling the GLOBAL source granule (rule #21).
// h_t written to the compact fp16 oH[N][128] plane (ping-pong, no race).
template<bool FIRST>
__global__ __launch_bounds__(256) void k_gates_cell(const _Float16* __restrict__ embt,
                                                    const _Float16* __restrict__ hcur,
                                                    const _Float16* __restrict__ Bt,
                                                    const float* __restrict__ bih,
                                                    const float* __restrict__ bhh,
                                                    float* __restrict__ cbuf,
                                                    _Float16* __restrict__ oH) {
  __shared__ _Float16 ls[2][8192];   // 2 x 16KB: [A 8KB | B 8KB]
  const int tid = threadIdx.x;
  const int lane = tid & 63, wid = tid >> 6;
  const int wr = wid >> 1, wc = wid & 1;
  const int lr = lane & 15;
  const int g  = lane >> 4;                 // k granule 0..3 (8 fp16 each)

  // bijective XCD-chunk swizzle (m204)
  int xcd = blockIdx.x & 7, loc = blockIdx.x >> 3;
  int wgid = (xcd < GRR ? xcd * (GQQ + 1) : GRR * (GQQ + 1) + (xcd - GRR) * GQQ) + loc;
  const int rb  = (wgid >> 2) * 128;
  const int ch0 = (wgid & 3) * 32;

  f32x4 acc[4][4];
  #pragma unroll
  for (int mi = 0; mi < 4; ++mi)
    #pragma unroll
    for (int ni = 0; ni < 4; ++ni) acc[mi][ni] = (f32x4)0.0f;

  // stage one 16KB k-block tile (async, no data registers)
  auto stage = [&](int buf, int kb) {
    const _Float16* srcA = (kb < 4) ? embt : hcur;   // both [N(P)][128]
    int koA = (kb & 3) * 32;
    int koB = kb * 32;
    _Float16* lb = &ls[buf][0];
    #pragma unroll
    for (int i = 0; i < 2; ++i) {
      int c = i * 256 + tid;               // 16B chunk id 0..511
      int row = c >> 2, slot = c & 3;
      int g3 = slot ^ ((row >> 1) & 3);    // pre-swizzled global granule
      size_t ga = (size_t)(rb + row) * H + koA + g3 * 8;
      gll16(srcA + ga, lb + c * 8);
      int j = (row >> 5) * 128 + ch0 + (row & 31);
      size_t gb = (size_t)j * 256 + koB + g3 * 8;
      gll16(Bt + gb, lb + 4096 + c * 8);
    }
  };

  auto compute = [&](int buf) {
    const _Float16* lb = &ls[buf][0];
    f16x8 bfr[4];
    #pragma unroll
    for (int ni = 0; ni < 4; ++ni) {
      int jj = ni * 32 + wc * 16 + lr;
      bfr[ni] = *(const f16x8*)(lb + 4096 + jj * 32 + (g ^ ((jj >> 1) & 3)) * 8);
    }
    #pragma unroll
    for (int mi = 0; mi < 4; ++mi) {
      int rr = wr * 64 + mi * 16 + lr;
      f16x8 afr = *(const f16x8*)(lb + rr * 32 + (g ^ ((rr >> 1) & 3)) * 8);
      #pragma unroll
      for (int ni = 0; ni < 4; ++ni)
        acc[mi][ni] = __builtin_amdgcn_mfma_f32_16x16x32_f16(afr, bfr[ni], acc[mi][ni], 0, 0, 0);
    }
  };

  const int kbs = FIRST ? 4 : 8;            // t=0: h==0, skip upper K half
  stage(0, 0);
  for (int kb = 0; kb < kbs; ++kb) {
    __syncthreads();                        // buf[kb&1] staged; prev reads done
    if (kb + 1 < kbs) stage((kb + 1) & 1, kb + 1);  // async, hides under MFMAs
    compute(kb & 1);
  }

  int ch = ch0 + wc * 16 + lr;
  float bi_ = bih[ch]       + bhh[ch];
  float bf_ = bih[128 + ch] + bhh[128 + ch];
  float bg_ = bih[256 + ch] + bhh[256 + ch];
  float bo_ = bih[384 + ch] + bhh[384 + ch];
  int orow = (lane >> 4) * 4;
  int rbw = rb + wr * 64;
  #pragma unroll
  for (int mi = 0; mi < 4; ++mi) {
    #pragma unroll
    for (int r = 0; r < 4; ++r) {
      int n = rbw + mi * 16 + orow + r;
      if (n >= N) continue;
      float gi = acc[mi][0][r] + bi_;
      float gf = acc[mi][1][r] + bf_;
      float gg = acc[mi][2][r] + bg_;
      float go = acc[mi][3][r] + bo_;
      float si = 1.f / (1.f + expf(-gi));
      float sf = 1.f / (1.f + expf(-gf));
      float so = 1.f / (1.f + expf(-go));
      float tg = tanhf(gg);
      size_t ci = (size_t)n * H + ch;
      float cn = FIRST ? si * tg : fmaf(sf, cbuf[ci], si * tg);
      cbuf[ci] = cn;
      float hn = so * tanhf(cn);
      oH[ci] = (_Float16)hn;
    }
  }
}

// ---------------- FC (MFMA): out[n][t][:] = h[n] @ W_fc^T + b_fc ----------------
// h fp16 from compact plane [N][128]; Wfc fp16 [32][128]. Wave = 64 rows x 32
// cols (mi=4, ni=2, 4 kblocks -> 32 MFMAs). Block 256 thr = 4 waves = 256 rows.
__global__ __launch_bounds__(256) void k_fc_mfma(const _Float16* __restrict__ Hc,
                                                 const _Float16* __restrict__ w16,
                                                 const float* __restrict__ bfc,
                                                 float* __restrict__ outp, int t) {
  int lane = threadIdx.x & 63, wid = threadIdx.x >> 6;
  int rb = blockIdx.x * 256 + wid * 64;
  int lr = lane & 15, g = lane >> 4;
  f32x4 acc[4][2];
  #pragma unroll
  for (int mi = 0; mi < 4; ++mi) { acc[mi][0] = (f32x4)0.0f; acc[mi][1] = (f32x4)0.0f; }

  #pragma unroll
  for (int kb = 0; kb < 4; ++kb) {
    int ko = kb * 32 + g * 8;
    f16x8 bfr[2];
    #pragma unroll
    for (int ni = 0; ni < 2; ++ni)
      bfr[ni] = *(const f16x8*)&w16[(ni * 16 + lr) * H + ko];
    #pragma unroll
    for (int mi = 0; mi < 4; ++mi) {
      int n = rb + mi * 16 + lr;
      n = n < N ? n : N - 1;               // clamp (pad rows discarded)
      f16x8 afr = *(const f16x8*)&Hc[(size_t)n * H + ko];
      #pragma unroll
      for (int ni = 0; ni < 2; ++ni)
        acc[mi][ni] = __builtin_amdgcn_mfma_f32_16x16x32_f16(afr, bfr[ni], acc[mi][ni], 0, 0, 0);
    }
  }
  int orow = g * 4;
  #pragma unroll
  for (int ni = 0; ni < 2; ++ni) {
    int oc = ni * 16 + lr;
    float bb = bfc[oc];
    #pragma unroll
    for (int mi = 0; mi < 4; ++mi)
      #pragma unroll
      for (int r = 0; r < 4; ++r) {
        int n = rb + mi * 16 + orow + r;
        if (n < N) outp[((size_t)n * T + t) * OUTD + oc] = acc[mi][ni][r] + bb;
      }
  }
}

// ---------------------------------------------------------------------------

extern "C" void kernel_launch(void* const* d_in, const int* in_sizes, int n_in,
                              void* d_out, int out_size, void* d_ws, size_t ws_size,
                              hipStream_t stream) {
  const float* x_seq = (const float*)d_in[0];
  const int*   eidx  = (const int*)d_in[1];
  const int*   erow  = eidx;          // sources
  const int*   ecol  = eidx + E;      // targets
  const float* W_gcn = (const float*)d_in[2];
  const float* b_gcn = (const float*)d_in[3];
  const float* W_ih  = (const float*)d_in[4];
  const float* W_hh  = (const float*)d_in[5];
  const float* b_ih  = (const float*)d_in[6];
  const float* b_hh  = (const float*)d_in[7];
  const float* W_fc  = (const float*)d_in[8];
  const float* b_fc  = (const float*)d_in[9];
  float* outp = (float*)d_out;

  char* base = (char*)d_ws;
  size_t o = 0;
  auto alloc = [&](size_t bytes) -> void* {
    void* p = base + o;
    o += (bytes + 255) & ~(size_t)255;
    return p;
  };
  int*   cnt      = (int*)  alloc((size_t)N * 4);
  int*   cursor   = (int*)  alloc((size_t)N * 4);
  int*   offv     = (int*)  alloc((size_t)(N + 1) * 4);
  int*   csum     = (int*)  alloc((size_t)(NCH + 1) * 4);
  int*   coff     = (int*)  alloc((size_t)(NCH + 1) * 4);
  float* dinv     = (float*)alloc((size_t)N * 4);
  int2*  csr      = (int2*) alloc((size_t)E * 8);
  _Float16* bt    = (_Float16*)alloc((size_t)G * 256 * 2);
  _Float16* bgT   = (_Float16*)alloc((size_t)H * H * 2);
  _Float16* wfc16 = (_Float16*)alloc((size_t)OUTD * H * 2);
  _Float16* xw_all = (_Float16*)alloc((size_t)T * N * H * 2);  // 115 MB
  _Float16* emb_all= (_Float16*)alloc((size_t)T * N * H * 2);  // 115 MB
  _Float16* h0    = (_Float16*)alloc((size_t)NP * H * 2);      // compact h, even t
  _Float16* h1    = (_Float16*)alloc((size_t)NP * H * 2);      // odd t
  float* cbuf     = (float*)alloc((size_t)N * H * 4);
  (void)ws_size; (void)in_sizes; (void)n_in; (void)out_size;

  _Float16* HP[2] = {h0, h1};

  // only the small CSR counters need zeroing; h/c state handled by the
  // FIRST-step specialization; pad rows only affect discarded output rows.
  hipMemsetAsync(cnt,    0, (size_t)N * 4, stream);
  hipMemsetAsync(cursor, 0, (size_t)N * 4, stream);

  k_count<<<E / 256, 256, 0, stream>>>(ecol, cnt);
  k_dinv<<<(N + 255) / 256, 256, 0, stream>>>(cnt, dinv);
  k_chunk_sum<<<NCH, SCAN_CH, 0, stream>>>(cnt, csum);
  k_chunk_scan<<<1, 64, 0, stream>>>(csum, coff);
  k_scan_final<<<NCH, SCAN_CH, 0, stream>>>(cnt, coff, offv);
  k_fill<<<E / 256, 256, 0, stream>>>(erow, ecol, dinv, offv, cursor, csr);
  k_wprep_lstm<<<(G * 256) / 256, 256, 0, stream>>>(W_ih, W_hh, bt);
  k_wprep_gcn<<<(H * H) / 256, 256, 0, stream>>>(W_gcn, bgT);
  k_wprep_fc<<<(OUTD * H + 255) / 256, 256, 0, stream>>>(W_fc, wfc16);

  // all 9 GCN GEMMs in one dispatch (no LSTM dependence)
  k_gcn_all<<<dim3(NP / 128, T), 256, 0, stream>>>(x_seq, bgT, xw_all);
  // whole aggregation phase in one dispatch (meta read once, 9 gathers)
  k_agg_all<<<N / 4, 256, 0, stream>>>(xw_all, offv, csr, dinv, b_gcn, emb_all);

  int fcblocks = (NP + 255) / 256;        // 196
  for (int t = 0; t < T; ++t) {
    int cur = t & 1, nxt = cur ^ 1;
    const _Float16* embt = emb_all + (size_t)t * N * H;
    if (t == 0)
      k_gates_cell<true><<<GNWG, 256, 0, stream>>>(
          embt, HP[cur], bt, b_ih, b_hh, cbuf, HP[nxt]);
    else
      k_gates_cell<false><<<GNWG, 256, 0, stream>>>(
          embt, HP[cur], bt, b_ih, b_hh, cbuf, HP[nxt]);
    k_fc_mfma<<<fcblocks, 256, 0, stream>>>(HP[nxt], wfc16, b_fc, outp, t);
  }
}